// Round 15
// baseline (1824.295 us; speedup 1.0000x reference)
//
#include <hip/hip_runtime.h>
#include <hip/hip_bf16.h>

#define NB 256   // batch
#define NS 512   // seq len
#define NV 4     // vocab
#define NH 512   // encoder hidden
#define CH 16    // steps per chunk
#define NCH 32   // chunks

typedef __bf16 bf16x8 __attribute__((ext_vector_type(8)));
typedef __bf16 bf16x4 __attribute__((ext_vector_type(4)));
typedef float  f32x4  __attribute__((ext_vector_type(4)));
typedef int    i32x4  __attribute__((ext_vector_type(4)));

// ---- workspace byte offsets ----
// flags 8KB | h1ring(i8) 4MB | zring(f32) 16MB | enc 512KB | cm/rs |
// frags_i8 3x256KB | scales 3x2KB | xzring(bf16) 8MB
#define H1RING_OFF  8192
#define ZRING_OFF   (H1RING_OFF + (4u << 20))
#define ENC_OFF     (ZRING_OFF + (16u << 20))
#define CM_OFF      (ENC_OFF + NB*NH*4)
#define RS_OFF      (CM_OFF + 2048)
#define FRAG_OFF    (RS_OFF + 2048)
#define SCALE_OFF   (FRAG_OFF + 3*262144)
#define XZRING_OFF  (SCALE_OFF + 8192)
// flags: F[g*16]=A prog, F[256+g*16]=B prog, F[512+g*32+c]=zdone, F[1024+g*32+c]=xzdone

__device__ __forceinline__ float fast_tanh(float x) {
    x = fminf(12.0f, fmaxf(-12.0f, x));
    float e = __expf(2.0f * x);
    return (e - 1.0f) / (e + 1.0f);
}

__device__ __forceinline__ int aload(int* p) {
    return __hip_atomic_load(p, __ATOMIC_ACQUIRE, __HIP_MEMORY_SCOPE_AGENT);
}

// ---------------------------------------------------------------------------
// One-shot: quantize weight matrices to int8 MFMA B-fragments (16x16x64 i8)
// with per-column scales.  frag layout: ((ks64*32 + gt)*64 + l)*16 bytes.
// ---------------------------------------------------------------------------
__global__ void prep_kernel(const float* __restrict__ W0, const float* __restrict__ W1,
                            const float* __restrict__ WG, char* __restrict__ ws)
{
    const int mt = blockIdx.x >> 5;     // 0=Whh0(A), 1=Whh1(B), 2=Wih1(G)
    const int gt = blockIdx.x & 31;
    const float* src = (mt == 0) ? W0 : (mt == 1) ? W1 : WG;
    char*  dst = ws + FRAG_OFF + (size_t)mt * 262144;
    float* fsc = (float*)(ws + SCALE_OFF) + mt * 512;
    const int tid = threadIdx.x;
    const int cg = tid >> 4, ti = tid & 15;

    __shared__ float cmax[16][17];
    __shared__ float inv[16];

    {
        const int col = gt * 16 + cg;
        float m = 0.f;
        for (int e = ti; e < NH; e += 16) m = fmaxf(m, fabsf(src[(size_t)col * NH + e]));
        cmax[cg][ti] = m;
    }
    __syncthreads();
    if (ti == 0) {
        float mm = 0.f;
#pragma unroll
        for (int j = 0; j < 16; ++j) mm = fmaxf(mm, cmax[cg][j]);
        inv[cg] = (mm > 0.f) ? 127.0f / mm : 0.f;
        fsc[gt * 16 + cg] = mm / (127.0f * 127.0f);
    }
    __syncthreads();

    for (int e = tid; e < 512; e += 256) {
        const int ks = e >> 6, l = e & 63;
        const int c16 = l & 15;
        const float iv = inv[c16];
        const float* p = src + (size_t)(gt * 16 + c16) * NH + ks * 64 + ((l >> 4) << 4);
        int vi[4];
#pragma unroll
        for (int w = 0; w < 4; ++w) {
            int b0 = __float2int_rn(p[w*4+0] * iv) & 255;
            int b1 = __float2int_rn(p[w*4+1] * iv) & 255;
            int b2 = __float2int_rn(p[w*4+2] * iv) & 255;
            int b3 = __float2int_rn(p[w*4+3] * iv) & 255;
            vi[w] = b0 | (b1 << 8) | (b2 << 16) | (b3 << 24);
        }
        *(i32x4*)(dst + ((size_t)(ks * 32 + gt) * 64 + l) * 16) = (i32x4){vi[0], vi[1], vi[2], vi[3]};
    }
}

// ---------------------------------------------------------------------------
// Persistent pipeline: 64 WGs x 512 threads, 1 block/CU.
// i8 weights CU-resident: ks64 0-3 VGPR (64 regs/wave), ks64 4-7 LDS (128KB
// at offset 24576).  NEW r15: X-role precomputes x@Wih0^T (bf16 ring) so the
// A chain is spill-free; af next-slab prefetch; G triple-buffer (1 barrier/t).
// role A (0-15): h1 chain | B (16-31): h2 chain | G (32-47): z | X (48-63): xz.
// ---------------------------------------------------------------------------
extern "C" __global__ __launch_bounds__(512, 1)
void persist_kernel(const float* __restrict__ x,
                    const float* __restrict__ eWih0,
                    const float* __restrict__ ebih0, const float* __restrict__ ebhh0,
                    const float* __restrict__ ebih1, const float* __restrict__ ebhh1,
                    char* __restrict__ ws)
{
    extern __shared__ char lds[];
    int*   F      = (int*)ws;
    char*  h1ring = ws + H1RING_OFF;
    char*  zring  = ws + ZRING_OFF;
    char*  xzring = ws + XZRING_OFF;
    float* enc    = (float*)(ws + ENC_OFF);

    const int blk  = blockIdx.x;
    const int role = blk >> 4;     // 0=A, 1=B, 2=G, 3=X
    const int g    = blk & 15;
    const int tid  = threadIdx.x;
    const int wq   = tid >> 6;     // wave 0..7
    const int l    = tid & 63;
    const int lm   = l & 15;
    const int q    = l >> 4;

    if (role == 3) {
        // ================= X role: xz[c] = x(t) @ Wih0^T + bias0 (bf16) ========
        bf16x8 EB[4];
        float  bias[4];
#pragma unroll
        for (int n = 0; n < 4; ++n) {
            const int col = wq * 64 + n * 16 + lm;
#pragma unroll
            for (int j = 0; j < 8; ++j) EB[n][j] = (__bf16)0.f;
            if (q == 0) {
                const float4 w0 = *(const float4*)(eWih0 + (size_t)col * NV);
                EB[n][0] = (__bf16)w0.x; EB[n][1] = (__bf16)w0.y;
                EB[n][2] = (__bf16)w0.z; EB[n][3] = (__bf16)w0.w;
            }
            bias[n] = ebih0[col] + ebhh0[col];
        }

#pragma unroll 1
        for (int c = 0; c < NCH; ++c) {
            if (c >= 2) {   // backpressure: A consumed xz chunk c-2
                if (tid == 0)
                    while (aload(&F[g * 16]) < c - 1) __builtin_amdgcn_s_sleep(2);
                __syncthreads();
            }
            char* xzsl = xzring + (size_t)((g * 2 + (c & 1)) * CH) * 16384;

#pragma unroll 1
            for (int t = 0; t < CH; ++t) {
                const int i = c * CH + t;
                const float4 xv = *(const float4*)(x + ((size_t)(g * 16 + lm) * NS + i) * NV);
                bf16x8 xa;
#pragma unroll
                for (int j = 0; j < 8; ++j) xa[j] = (__bf16)0.f;
                if (q == 0) {
                    xa[0] = (__bf16)xv.x; xa[1] = (__bf16)xv.y;
                    xa[2] = (__bf16)xv.z; xa[3] = (__bf16)xv.w;
                }
#pragma unroll
                for (int n = 0; n < 4; ++n) {
                    f32x4 a = (f32x4){bias[n], bias[n], bias[n], bias[n]};
                    a = __builtin_amdgcn_mfma_f32_16x16x32_bf16(xa, EB[n], a, 0, 0, 0);
                    bf16x4 o;
#pragma unroll
                    for (int jr = 0; jr < 4; ++jr) o[jr] = (__bf16)a[jr];
                    __builtin_nontemporal_store(o,
                        (bf16x4*)(xzsl + (size_t)t * 16384 + ((wq * 4 + n) * 64 + l) * 8));
                }
            }
            __syncthreads();
            if (tid == 0)
                __hip_atomic_store(&F[1024 + g * 32 + c], 1, __ATOMIC_RELEASE, __HIP_MEMORY_SCOPE_AGENT);
        }
        return;
    }

    const int mt = role;   // 0=Whh0, 1=Whh1, 2=Wih1
    const char*  frag = ws + FRAG_OFF + (size_t)mt * 262144;
    const float* fsc  = (const float*)(ws + SCALE_OFF) + mt * 512;

    char* HS = lds;            // chain: h_i8 dbuf 2x8KB; G: 3x8KB triple buffer
    char* WL = lds + 24576;    // ks64 4..7 i8 slabs (4 x 32KB)

    // ---- weights: ks64 0-3 resident in VGPR, ks64 4-7 into LDS ----
    i32x4 WR[4][4];
#pragma unroll
    for (int ks = 0; ks < 4; ++ks)
#pragma unroll
        for (int n = 0; n < 4; ++n)
            WR[ks][n] = *(const i32x4*)(frag + ((size_t)(ks * 32 + wq * 4 + n) * 64 + l) * 16);
#pragma unroll
    for (int ks = 4; ks < 8; ++ks)
#pragma unroll
        for (int n = 0; n < 4; ++n) {
            const i32x4 v = *(const i32x4*)(frag + ((size_t)(ks * 32 + wq * 4 + n) * 64 + l) * 16);
            *(i32x4*)(WL + (((ks - 4) * 32 + wq * 4 + n) * 64 + l) * 16) = v;
        }
    float f[4];
#pragma unroll
    for (int n = 0; n < 4; ++n) f[n] = fsc[wq * 64 + n * 16 + lm];

    if (role <= 1) {
        // ================= chain roles (A: layer-0, B: layer-1) =================
        const bool isA = (role == 0);

        // zero h_i8 state (both buffers, 16 KB)
        *(f32x4*)(HS + tid * 32)      = (f32x4){0.f, 0.f, 0.f, 0.f};
        *(f32x4*)(HS + tid * 32 + 16) = (f32x4){0.f, 0.f, 0.f, 0.f};
        __syncthreads();

#pragma unroll 1
        for (int c = 0; c < NCH; ++c) {
            // ---- chunk-entry sync ----
            if (isA) {
                if (tid == 0) {
                    while (aload(&F[1024 + g * 32 + c]) < 1) __builtin_amdgcn_s_sleep(2);
                    if (c >= 2)   // backpressure: G consumed h1 chunk c-2
                        while (aload(&F[512 + g * 32 + (c - 2)]) < 1) __builtin_amdgcn_s_sleep(2);
                }
                __syncthreads();
                __builtin_amdgcn_fence(__ATOMIC_ACQUIRE, "agent");
            } else {
                if (tid == 0)
                    while (aload(&F[512 + g * 32 + c]) < 1) __builtin_amdgcn_s_sleep(2);
                __syncthreads();
                __builtin_amdgcn_fence(__ATOMIC_ACQUIRE, "agent");
            }

            char* rsl  = h1ring + (size_t)((g * 2 + (c & 1)) * CH) * 8192;   // A writes (i8)
            char* zsl  = zring  + (size_t)((g * 2 + (c & 1)) * CH) * 32768;  // B reads (f32)
            char* xzsl = xzring + (size_t)((g * 2 + (c & 1)) * CH) * 16384;  // A reads (bf16)

            f32x4  zn[4];
            bf16x4 xzn[4];
            if (isA) {
#pragma unroll
                for (int n = 0; n < 4; ++n)
                    xzn[n] = __builtin_nontemporal_load(
                        (const bf16x4*)(xzsl + ((wq * 4 + n) * 64 + l) * 8));
            } else {
#pragma unroll
                for (int n = 0; n < 4; ++n)
                    zn[n] = __builtin_nontemporal_load(
                        (const f32x4*)(zsl + ((wq * 4 + n) * 64 + l) * 16));
            }

#pragma unroll 1
            for (int t = 0; t < CH; ++t) {
                const int i  = c * CH + t;
                const int rb = t & 1;
                const char* hsr = HS + rb * 8192;
                char*       hsw = HS + (rb ^ 1) * 8192;

                f32x4 base[4];
                if (isA) {
#pragma unroll
                    for (int n = 0; n < 4; ++n) {
#pragma unroll
                        for (int jr = 0; jr < 4; ++jr) base[n][jr] = (float)xzn[n][jr];
                    }
                    if (t + 1 < CH) {
#pragma unroll
                        for (int n = 0; n < 4; ++n)
                            xzn[n] = __builtin_nontemporal_load(
                                (const bf16x4*)(xzsl + (size_t)(t + 1) * 16384 +
                                                ((wq * 4 + n) * 64 + l) * 8));
                    }
                } else {
#pragma unroll
                    for (int n = 0; n < 4; ++n) base[n] = zn[n];
                    if (t + 1 < CH) {
#pragma unroll
                        for (int n = 0; n < 4; ++n)
                            zn[n] = __builtin_nontemporal_load(
                                (const f32x4*)(zsl + (size_t)(t + 1) * 32768 +
                                               ((wq * 4 + n) * 64 + l) * 16));
                    }
                }

                // ---- K-sweep: 4 resident + 4 LDS, af next-slab prefetch ----
                i32x4 acc[4];
#pragma unroll
                for (int n = 0; n < 4; ++n) acc[n] = (i32x4){0, 0, 0, 0};

                __builtin_amdgcn_s_setprio(1);
                i32x4 afc = *(const i32x4*)(hsr + l * 16);
#pragma unroll
                for (int ks = 0; ks < 8; ++ks) {
                    i32x4 afn;
                    if (ks < 7) afn = *(const i32x4*)(hsr + (ks + 1) * 1024 + l * 16);
                    if (ks < 4) {
#pragma unroll
                        for (int n = 0; n < 4; ++n)
                            acc[n] = __builtin_amdgcn_mfma_i32_16x16x64_i8(afc, WR[ks][n], acc[n], 0, 0, 0);
                    } else {
#pragma unroll
                        for (int n = 0; n < 4; ++n) {
                            const i32x4 bfr = *(const i32x4*)(WL + (((ks - 4) * 32 + wq * 4 + n) * 64 + l) * 16);
                            acc[n] = __builtin_amdgcn_mfma_i32_16x16x64_i8(afc, bfr, acc[n], 0, 0, 0);
                        }
                    }
                    afc = afn;
                }
                __builtin_amdgcn_s_setprio(0);

                // ---- dequant + epilogue ----
                if (!isA && i == NS - 1) {
                    // encoded = PRE-tanh (arctanh(tanh(s)) == s)
#pragma unroll
                    for (int n = 0; n < 4; ++n) {
                        const int col = wq * 64 + n * 16 + lm;
#pragma unroll
                        for (int jr = 0; jr < 4; ++jr)
                            enc[(size_t)(g * 16 + q * 4 + jr) * NH + col] =
                                base[n][jr] + (float)acc[n][jr] * f[n];
                    }
                } else {
#pragma unroll
                    for (int n = 0; n < 4; ++n) {
#pragma unroll
                        for (int jr = 0; jr < 4; ++jr) {
                            const float s  = base[n][jr] + (float)acc[n][jr] * f[n];
                            const float th = fast_tanh(s);
                            const int slot = (q * 4 + jr) | (n << 4);
                            *(char*)(hsw + wq * 1024 + slot * 16 + lm) =
                                (char)__float2int_rn(th * 127.0f);
                        }
                    }
                }
                __syncthreads();  // hsw complete for all waves

                if (isA) {
                    const i32x4 v = *(const i32x4*)(hsw + tid * 16);
                    __builtin_nontemporal_store(v, (i32x4*)(rsl + (size_t)t * 8192 + tid * 16));
                }
            }

            // ---- chunk-exit publish ----
            __syncthreads();
            if (tid == 0) {
                if (isA)
                    __hip_atomic_store(&F[g * 16], c + 1, __ATOMIC_RELEASE, __HIP_MEMORY_SCOPE_AGENT);
                else
                    __hip_atomic_store(&F[256 + g * 16], c + 1, __ATOMIC_RELEASE, __HIP_MEMORY_SCOPE_AGENT);
            }
        }
    } else {
        // ================= G role: z[c] = h1[c] @ Wih1^T + bias =================
        float bv[4];
#pragma unroll
        for (int n = 0; n < 4; ++n) {
            const int col = wq * 64 + n * 16 + lm;
            bv[n] = ebih1[col] + ebhh1[col];
        }
        __syncthreads();

#pragma unroll 1
        for (int c = 0; c < NCH; ++c) {
            if (tid == 0) {
                while (aload(&F[g * 16]) < c + 1) __builtin_amdgcn_s_sleep(2);
                if (c >= 2)
                    while (aload(&F[256 + g * 16]) < c - 1) __builtin_amdgcn_s_sleep(2);
            }
            __syncthreads();
            __builtin_amdgcn_fence(__ATOMIC_ACQUIRE, "agent");

            const char* rsl = h1ring + (size_t)((g * 2 + (c & 1)) * CH) * 8192;
            char*       zsl = zring  + (size_t)((g * 2 + (c & 1)) * CH) * 32768;

            // stage t=0 into slab 0 (triple-buffer rotation: read t%3, write (t+1)%3)
            *(i32x4*)(HS + tid * 16) =
                __builtin_nontemporal_load((const i32x4*)(rsl + tid * 16));
            __syncthreads();

#pragma unroll 1
            for (int t = 0; t < CH; ++t) {
                const char* bufr = HS + (t % 3) * 8192;
                char*       bufw = HS + ((t + 1) % 3) * 8192;
                i32x4 p0;
                const bool pf = (t + 1 < CH);
                if (pf) p0 = __builtin_nontemporal_load(
                            (const i32x4*)(rsl + (size_t)(t + 1) * 8192 + tid * 16));

                i32x4 acc[4];
#pragma unroll
                for (int n = 0; n < 4; ++n) acc[n] = (i32x4){0, 0, 0, 0};

                __builtin_amdgcn_s_setprio(1);
                i32x4 afc = *(const i32x4*)(bufr + l * 16);
#pragma unroll
                for (int ks = 0; ks < 8; ++ks) {
                    i32x4 afn;
                    if (ks < 7) afn = *(const i32x4*)(bufr + (ks + 1) * 1024 + l * 16);
                    if (ks < 4) {
#pragma unroll
                        for (int n = 0; n < 4; ++n)
                            acc[n] = __builtin_amdgcn_mfma_i32_16x16x64_i8(afc, WR[ks][n], acc[n], 0, 0, 0);
                    } else {
#pragma unroll
                        for (int n = 0; n < 4; ++n) {
                            const i32x4 bfr = *(const i32x4*)(WL + (((ks - 4) * 32 + wq * 4 + n) * 64 + l) * 16);
                            acc[n] = __builtin_amdgcn_mfma_i32_16x16x64_i8(afc, bfr, acc[n], 0, 0, 0);
                        }
                    }
                    afc = afn;
                }
                __builtin_amdgcn_s_setprio(0);

#pragma unroll
                for (int n = 0; n < 4; ++n) {
                    f32x4 zv;
#pragma unroll
                    for (int jr = 0; jr < 4; ++jr) zv[jr] = bv[n] + (float)acc[n][jr] * f[n];
                    __builtin_nontemporal_store(zv,
                        (f32x4*)(zsl + (size_t)t * 32768 + ((wq * 4 + n) * 64 + l) * 16));
                }

                if (pf) *(i32x4*)(bufw + tid * 16) = p0;   // stage next slab
                __syncthreads();   // single barrier: bounds skew to 1 step (3-deep safe)
            }

            if (tid == 0)
                __hip_atomic_store(&F[512 + g * 32 + c], 1, __ATOMIC_RELEASE, __HIP_MEMORY_SCOPE_AGENT);
        }
    }
}

// ---------------------------------------------------------------------------
// Batch-axis softmax stats per hidden column.
// ---------------------------------------------------------------------------
__global__ void colstats_kernel(const float* __restrict__ encoded,
                                float* __restrict__ colmax,
                                float* __restrict__ rsinv)
{
    const int h = blockIdx.x;
    const int lane = threadIdx.x;  // 64
    float v[4];
#pragma unroll
    for (int r = 0; r < 4; ++r) v[r] = encoded[(size_t)(lane + 64 * r) * NH + h];
    float mx = fmaxf(fmaxf(v[0], v[1]), fmaxf(v[2], v[3]));
#pragma unroll
    for (int s = 1; s < 64; s <<= 1) mx = fmaxf(mx, __shfl_xor(mx, s));
    float sum = 0.f;
#pragma unroll
    for (int r = 0; r < 4; ++r) sum += __expf(v[r] - mx);
#pragma unroll
    for (int s = 1; s < 64; s <<= 1) sum += __shfl_xor(sum, s);
    if (lane == 0) { colmax[h] = mx; rsinv[h] = 1.0f / sum; }
}

// ---------------------------------------------------------------------------
// Decoder: one batch element per thread; 4-dim recurrence in registers.
// ---------------------------------------------------------------------------
__global__ void decoder_kernel(
    const float* __restrict__ encoded,
    const float* __restrict__ colmax, const float* __restrict__ rsinv,
    const float* __restrict__ dWih0, const float* __restrict__ dWhh0,
    const float* __restrict__ dbih0, const float* __restrict__ dbhh0,
    const float* __restrict__ dWih1, const float* __restrict__ dWhh1,
    const float* __restrict__ dbih1, const float* __restrict__ dbhh1,
    float* __restrict__ out)
{
    const int b = blockIdx.x * 64 + threadIdx.x;

    float W0[16], Wi[16], W1[16];
#pragma unroll
    for (int e = 0; e < 16; ++e) { W0[e] = dWhh0[e]; Wi[e] = dWih1[e]; W1[e] = dWhh1[e]; }

    float c1[4], c2[4];
#pragma unroll
    for (int j = 0; j < 4; ++j) { c1[j] = dbih0[j] + dbhh0[j]; c2[j] = dbih1[j] + dbhh1[j]; }

    const float* er = encoded + (size_t)b * NH;
#pragma unroll 1
    for (int h = 0; h < NH; h += 4) {
        const float4 ev = *(const float4*)(er + h);
        const float4 cm = *(const float4*)(colmax + h);
        const float4 rs = *(const float4*)(rsinv + h);
        float p0 = __expf(ev.x - cm.x) * rs.x;
        float p1 = __expf(ev.y - cm.y) * rs.y;
        float p2 = __expf(ev.z - cm.z) * rs.z;
        float p3 = __expf(ev.w - cm.w) * rs.w;
#pragma unroll
        for (int j = 0; j < 4; ++j) {
            const float4 w = *(const float4*)(dWih0 + (size_t)j * NH + h);
            c1[j] += p0 * w.x + p1 * w.y + p2 * w.z + p3 * w.w;
        }
    }

    float h1[4] = {0.f, 0.f, 0.f, 0.f};
    float h2[4] = {0.f, 0.f, 0.f, 0.f};
    float* op = out + (size_t)b * NS * NV;

#pragma unroll 1
    for (int t = 0; t < NS; ++t) {
        float n1[4];
#pragma unroll
        for (int j = 0; j < 4; ++j)
            n1[j] = fast_tanh(c1[j] + W0[j*4+0]*h1[0] + W0[j*4+1]*h1[1]
                                    + W0[j*4+2]*h1[2] + W0[j*4+3]*h1[3]);
        float n2[4];
#pragma unroll
        for (int j = 0; j < 4; ++j)
            n2[j] = fast_tanh(c2[j] + Wi[j*4+0]*n1[0] + Wi[j*4+1]*n1[1]
                                    + Wi[j*4+2]*n1[2] + Wi[j*4+3]*n1[3]
                                    + W1[j*4+0]*h2[0] + W1[j*4+1]*h2[1]
                                    + W1[j*4+2]*h2[2] + W1[j*4+3]*h2[3]);
#pragma unroll
        for (int j = 0; j < 4; ++j) { h1[j] = n1[j]; h2[j] = n2[j]; }
        *(float4*)(op + (size_t)t * NV) = make_float4(n2[0], n2[1], n2[2], n2[3]);
    }
}

extern "C" void kernel_launch(void* const* d_in, const int* in_sizes, int n_in,
                              void* d_out, int out_size, void* d_ws, size_t ws_size,
                              hipStream_t stream)
{
    const float* x     = (const float*)d_in[0];
    const float* eWih0 = (const float*)d_in[1];
    const float* eWhh0 = (const float*)d_in[2];
    const float* ebih0 = (const float*)d_in[3];
    const float* ebhh0 = (const float*)d_in[4];
    const float* eWih1 = (const float*)d_in[5];
    const float* eWhh1 = (const float*)d_in[6];
    const float* ebih1 = (const float*)d_in[7];
    const float* ebhh1 = (const float*)d_in[8];
    const float* dWih0 = (const float*)d_in[9];
    const float* dWhh0 = (const float*)d_in[10];
    const float* dbih0 = (const float*)d_in[11];
    const float* dbhh0 = (const float*)d_in[12];
    const float* dWih1 = (const float*)d_in[13];
    const float* dWhh1 = (const float*)d_in[14];
    const float* dbih1 = (const float*)d_in[15];
    const float* dbhh1 = (const float*)d_in[16];

    char*  ws     = (char*)d_ws;
    float* enc    = (float*)(ws + ENC_OFF);
    float* colmax = (float*)(ws + CM_OFF);
    float* rsinv  = (float*)(ws + RS_OFF);

    hipFuncSetAttribute((const void*)persist_kernel,
                        hipFuncAttributeMaxDynamicSharedMemorySize, 155648);

    // zero flags
    hipMemsetAsync(d_ws, 0, 8192, stream);

    // one-shot weight quantization (i8 B-frags + per-col scales)
    prep_kernel<<<96, 256, 0, stream>>>(eWhh0, eWhh1, eWih1, ws);

    // persistent pipelined encoder (A, B, G, X roles)
    persist_kernel<<<64, 512, 155648, stream>>>(x, eWih0, ebih0, ebhh0,
                                                ebih1, ebhh1, ws);

    colstats_kernel<<<NH, 64, 0, stream>>>(enc, colmax, rsinv);
    decoder_kernel<<<4, 64, 0, stream>>>(enc, colmax, rsinv,
                                         dWih0, dWhh0, dbih0, dbhh0,
                                         dWih1, dWhh1, dbih1, dbhh1,
                                         (float*)d_out);
}

// Round 16
// 1704.855 us; speedup vs baseline: 1.0701x; 1.0701x over previous
//
#include <hip/hip_runtime.h>
#include <hip/hip_bf16.h>

#define NB 256   // batch
#define NS 512   // seq len
#define NV 4     // vocab
#define NH 512   // encoder hidden
#define CH 16    // steps per chunk
#define NCH 32   // chunks

typedef __bf16 bf16x8 __attribute__((ext_vector_type(8)));
typedef float  f32x4  __attribute__((ext_vector_type(4)));
typedef int    i32x4  __attribute__((ext_vector_type(4)));

// ---- workspace byte offsets ----
// flags 8KB | h1ring(i8) 4MB | zring(f32) 16MB | enc 512KB | cm/rs |
// frags_i8 3x256KB | scales 3x2KB
#define H1RING_OFF  8192
#define ZRING_OFF   (H1RING_OFF + (4u << 20))
#define ENC_OFF     (ZRING_OFF + (16u << 20))
#define CM_OFF      (ENC_OFF + NB*NH*4)
#define RS_OFF      (CM_OFF + 2048)
#define FRAG_OFF    (RS_OFF + 2048)
#define SCALE_OFF   (FRAG_OFF + 3*262144)
// flags: F[g*16]=A prog, F[256+g*16]=B prog, F[512+g*32+c]=zdone

__device__ __forceinline__ float fast_tanh(float x) {
    x = fminf(12.0f, fmaxf(-12.0f, x));
    float e = __expf(2.0f * x);
    return (e - 1.0f) / (e + 1.0f);
}

__device__ __forceinline__ int aload(int* p) {
    return __hip_atomic_load(p, __ATOMIC_ACQUIRE, __HIP_MEMORY_SCOPE_AGENT);
}

// ---------------------------------------------------------------------------
// One-shot: quantize weight matrices to int8 MFMA B-fragments (16x16x64 i8)
// with per-column scales.  frag layout: ((ks64*32 + gt)*64 + l)*16 bytes.
// ---------------------------------------------------------------------------
__global__ void prep_kernel(const float* __restrict__ W0, const float* __restrict__ W1,
                            const float* __restrict__ WG, char* __restrict__ ws)
{
    const int mt = blockIdx.x >> 5;     // 0=Whh0(A), 1=Whh1(B), 2=Wih1(G)
    const int gt = blockIdx.x & 31;
    const float* src = (mt == 0) ? W0 : (mt == 1) ? W1 : WG;
    char*  dst = ws + FRAG_OFF + (size_t)mt * 262144;
    float* fsc = (float*)(ws + SCALE_OFF) + mt * 512;
    const int tid = threadIdx.x;
    const int cg = tid >> 4, ti = tid & 15;

    __shared__ float cmax[16][17];
    __shared__ float inv[16];

    {
        const int col = gt * 16 + cg;
        float m = 0.f;
        for (int e = ti; e < NH; e += 16) m = fmaxf(m, fabsf(src[(size_t)col * NH + e]));
        cmax[cg][ti] = m;
    }
    __syncthreads();
    if (ti == 0) {
        float mm = 0.f;
#pragma unroll
        for (int j = 0; j < 16; ++j) mm = fmaxf(mm, cmax[cg][j]);
        inv[cg] = (mm > 0.f) ? 127.0f / mm : 0.f;
        fsc[gt * 16 + cg] = mm / (127.0f * 127.0f);
    }
    __syncthreads();

    for (int e = tid; e < 512; e += 256) {
        const int ks = e >> 6, l = e & 63;
        const int c16 = l & 15;
        const float iv = inv[c16];
        const float* p = src + (size_t)(gt * 16 + c16) * NH + ks * 64 + ((l >> 4) << 4);
        int vi[4];
#pragma unroll
        for (int w = 0; w < 4; ++w) {
            int b0 = __float2int_rn(p[w*4+0] * iv) & 255;
            int b1 = __float2int_rn(p[w*4+1] * iv) & 255;
            int b2 = __float2int_rn(p[w*4+2] * iv) & 255;
            int b3 = __float2int_rn(p[w*4+3] * iv) & 255;
            vi[w] = b0 | (b1 << 8) | (b2 << 16) | (b3 << 24);
        }
        *(i32x4*)(dst + ((size_t)(ks * 32 + gt) * 64 + l) * 16) = (i32x4){vi[0], vi[1], vi[2], vi[3]};
    }
}

// ---------------------------------------------------------------------------
// Persistent pipeline: 48 WGs x 512 threads, 1 block/CU (r14 sync graph).
// i8 weights CU-resident: ks64 0-3 VGPR (64 regs/wave), ks64 4-7 LDS (128KB).
// r16 = r14 + {af next-slab prefetch, s_setprio around MFMA sweep, G-role
// triple-buffered staging with 1 barrier/step}.  (r15's X-role reverted:
// its ring+sync cost exceeded the 4-MFMA saving on the A chain.)
// role A (0-15): h1 chain | B (16-31): h2 chain | G (32-47): z.
// ---------------------------------------------------------------------------
extern "C" __global__ __launch_bounds__(512, 1)
void persist_kernel(const float* __restrict__ x,
                    const float* __restrict__ eWih0,
                    const float* __restrict__ ebih0, const float* __restrict__ ebhh0,
                    const float* __restrict__ ebih1, const float* __restrict__ ebhh1,
                    char* __restrict__ ws)
{
    extern __shared__ char lds[];
    int*   F      = (int*)ws;
    char*  h1ring = ws + H1RING_OFF;
    char*  zring  = ws + ZRING_OFF;
    float* enc    = (float*)(ws + ENC_OFF);

    const int blk  = blockIdx.x;
    const int role = blk >> 4;     // 0=A, 1=B, 2=G
    const int g    = blk & 15;
    const int tid  = threadIdx.x;
    const int wq   = tid >> 6;     // wave 0..7
    const int l    = tid & 63;
    const int lm   = l & 15;
    const int q    = l >> 4;

    const int mt = role;   // 0=Whh0, 1=Whh1, 2=Wih1
    const char*  frag = ws + FRAG_OFF + (size_t)mt * 262144;
    const float* fsc  = (const float*)(ws + SCALE_OFF) + mt * 512;

    char* HS = lds;            // chains: h_i8 dbuf 2x8KB; G: 3x8KB triple buffer
    char* WL = lds + 24576;    // ks64 4..7 i8 slabs (4 x 32KB)

    // ---- weights: ks64 0-3 resident in VGPR, ks64 4-7 into LDS ----
    i32x4 WR[4][4];
#pragma unroll
    for (int ks = 0; ks < 4; ++ks)
#pragma unroll
        for (int n = 0; n < 4; ++n)
            WR[ks][n] = *(const i32x4*)(frag + ((size_t)(ks * 32 + wq * 4 + n) * 64 + l) * 16);
#pragma unroll
    for (int ks = 4; ks < 8; ++ks)
#pragma unroll
        for (int n = 0; n < 4; ++n) {
            const i32x4 v = *(const i32x4*)(frag + ((size_t)(ks * 32 + wq * 4 + n) * 64 + l) * 16);
            *(i32x4*)(WL + (((ks - 4) * 32 + wq * 4 + n) * 64 + l) * 16) = v;
        }
    float f[4];
#pragma unroll
    for (int n = 0; n < 4; ++n) f[n] = fsc[wq * 64 + n * 16 + lm];

    if (role <= 1) {
        // ================= chain roles (A: layer-0, B: layer-1) =================
        const bool isA = (role == 0);

        // zero h_i8 state (both buffers, 16 KB)
        *(f32x4*)(HS + tid * 32)      = (f32x4){0.f, 0.f, 0.f, 0.f};
        *(f32x4*)(HS + tid * 32 + 16) = (f32x4){0.f, 0.f, 0.f, 0.f};

        bf16x8 EB[4];
        float  bias[4];
#pragma unroll
        for (int n = 0; n < 4; ++n) {
            const int col = wq * 64 + n * 16 + lm;
#pragma unroll
            for (int j = 0; j < 8; ++j) EB[n][j] = (__bf16)0.f;
            if (isA) {
                if (q == 0) {
                    const float4 w0 = *(const float4*)(eWih0 + (size_t)col * NV);
                    EB[n][0] = (__bf16)w0.x; EB[n][1] = (__bf16)w0.y;
                    EB[n][2] = (__bf16)w0.z; EB[n][3] = (__bf16)w0.w;
                }
                bias[n] = ebih0[col] + ebhh0[col];
            } else {
                bias[n] = 0.f;  // z already contains layer-1 biases
            }
        }
        __syncthreads();

#pragma unroll 1
        for (int c = 0; c < NCH; ++c) {
            // ---- chunk-entry sync ----
            if (isA) {
                if (c >= 2) {   // backpressure: G consumed h1 chunk c-2 (same parity)
                    if (tid == 0)
                        while (aload(&F[512 + g * 32 + (c - 2)]) < 1)
                            __builtin_amdgcn_s_sleep(2);
                    __syncthreads();
                }
            } else {
                if (tid == 0)
                    while (aload(&F[512 + g * 32 + c]) < 1)
                        __builtin_amdgcn_s_sleep(2);
                __syncthreads();
                __builtin_amdgcn_fence(__ATOMIC_ACQUIRE, "agent");
            }

            char* rsl = h1ring + (size_t)((g * 2 + (c & 1)) * CH) * 8192;   // A writes (i8)
            char* zsl = zring  + (size_t)((g * 2 + (c & 1)) * CH) * 32768;  // B reads (f32)

            f32x4 zn[4];
            if (!isA) {
#pragma unroll
                for (int n = 0; n < 4; ++n)
                    zn[n] = __builtin_nontemporal_load(
                        (const f32x4*)(zsl + ((wq * 4 + n) * 64 + l) * 16));
            }

#pragma unroll 1
            for (int t = 0; t < CH; ++t) {
                const int i  = c * CH + t;
                const int rb = t & 1;
                const char* hsr = HS + rb * 8192;
                char*       hsw = HS + (rb ^ 1) * 8192;

                i32x4 acc[4];
#pragma unroll
                for (int n = 0; n < 4; ++n) acc[n] = (i32x4){0, 0, 0, 0};
                f32x4 xacc[4];
                bf16x8 xa;
                if (isA) {
#pragma unroll
                    for (int n = 0; n < 4; ++n)
                        xacc[n] = (f32x4){bias[n], bias[n], bias[n], bias[n]};
                    const float4 xv = *(const float4*)(x + ((size_t)(g * 16 + lm) * NS + i) * NV);
#pragma unroll
                    for (int j = 0; j < 8; ++j) xa[j] = (__bf16)0.f;
                    if (q == 0) {
                        xa[0] = (__bf16)xv.x; xa[1] = (__bf16)xv.y;
                        xa[2] = (__bf16)xv.z; xa[3] = (__bf16)xv.w;
                    }
#pragma unroll
                    for (int n = 0; n < 4; ++n)
                        xacc[n] = __builtin_amdgcn_mfma_f32_16x16x32_bf16(xa, EB[n], xacc[n], 0, 0, 0);
                } else {
#pragma unroll
                    for (int n = 0; n < 4; ++n) xacc[n] = zn[n];
                    if (t + 1 < CH) {
#pragma unroll
                        for (int n = 0; n < 4; ++n)
                            zn[n] = __builtin_nontemporal_load(
                                (const f32x4*)(zsl + (size_t)(t + 1) * 32768 +
                                               ((wq * 4 + n) * 64 + l) * 16));
                    }
                }

                // ---- K-sweep: 4 resident + 4 LDS, af next-slab prefetch ----
                __builtin_amdgcn_s_setprio(1);
                i32x4 afc = *(const i32x4*)(hsr + l * 16);
#pragma unroll
                for (int ks = 0; ks < 8; ++ks) {
                    i32x4 afn;
                    if (ks < 7) afn = *(const i32x4*)(hsr + (ks + 1) * 1024 + l * 16);
                    if (ks < 4) {
#pragma unroll
                        for (int n = 0; n < 4; ++n)
                            acc[n] = __builtin_amdgcn_mfma_i32_16x16x64_i8(afc, WR[ks][n], acc[n], 0, 0, 0);
                    } else {
#pragma unroll
                        for (int n = 0; n < 4; ++n) {
                            const i32x4 bfr = *(const i32x4*)(WL + (((ks - 4) * 32 + wq * 4 + n) * 64 + l) * 16);
                            acc[n] = __builtin_amdgcn_mfma_i32_16x16x64_i8(afc, bfr, acc[n], 0, 0, 0);
                        }
                    }
                    afc = afn;
                }
                __builtin_amdgcn_s_setprio(0);

                // ---- dequant + epilogue ----
                if (!isA && i == NS - 1) {
                    // encoded = PRE-tanh (arctanh(tanh(s)) == s)
#pragma unroll
                    for (int n = 0; n < 4; ++n) {
                        const int col = wq * 64 + n * 16 + lm;
#pragma unroll
                        for (int jr = 0; jr < 4; ++jr)
                            enc[(size_t)(g * 16 + q * 4 + jr) * NH + col] =
                                xacc[n][jr] + (float)acc[n][jr] * f[n];
                    }
                } else {
#pragma unroll
                    for (int n = 0; n < 4; ++n) {
#pragma unroll
                        for (int jr = 0; jr < 4; ++jr) {
                            const float s  = xacc[n][jr] + (float)acc[n][jr] * f[n];
                            const float th = fast_tanh(s);
                            const int slot = (q * 4 + jr) | (n << 4);
                            *(char*)(hsw + wq * 1024 + slot * 16 + lm) =
                                (char)__float2int_rn(th * 127.0f);
                        }
                    }
                }
                __syncthreads();  // hsw complete for all waves

                if (isA) {
                    const i32x4 v = *(const i32x4*)(hsw + tid * 16);
                    __builtin_nontemporal_store(v, (i32x4*)(rsl + (size_t)t * 8192 + tid * 16));
                }
            }

            // ---- chunk-exit publish ----
            __syncthreads();
            if (tid == 0) {
                if (isA)
                    __hip_atomic_store(&F[g * 16], c + 1, __ATOMIC_RELEASE, __HIP_MEMORY_SCOPE_AGENT);
                else
                    __hip_atomic_store(&F[256 + g * 16], c + 1, __ATOMIC_RELEASE, __HIP_MEMORY_SCOPE_AGENT);
            }
        }
    } else {
        // ================= G role: z[c] = h1[c] @ Wih1^T + bias =================
        float bv[4];
#pragma unroll
        for (int n = 0; n < 4; ++n) {
            const int col = wq * 64 + n * 16 + lm;
            bv[n] = ebih1[col] + ebhh1[col];
        }
        __syncthreads();

#pragma unroll 1
        for (int c = 0; c < NCH; ++c) {
            if (tid == 0) {
                while (aload(&F[g * 16]) < c + 1) __builtin_amdgcn_s_sleep(2);
                if (c >= 2)
                    while (aload(&F[256 + g * 16]) < c - 1) __builtin_amdgcn_s_sleep(2);
            }
            __syncthreads();
            __builtin_amdgcn_fence(__ATOMIC_ACQUIRE, "agent");

            const char* rsl = h1ring + (size_t)((g * 2 + (c & 1)) * CH) * 8192;
            char*       zsl = zring  + (size_t)((g * 2 + (c & 1)) * CH) * 32768;

            // stage t=0 into slab 0 (triple buffer: read t%3, stage into (t+1)%3)
            *(i32x4*)(HS + tid * 16) =
                __builtin_nontemporal_load((const i32x4*)(rsl + tid * 16));
            __syncthreads();

#pragma unroll 1
            for (int t = 0; t < CH; ++t) {
                const char* bufr = HS + (t % 3) * 8192;
                char*       bufw = HS + ((t + 1) % 3) * 8192;
                i32x4 p0;
                const bool pf = (t + 1 < CH);
                if (pf) p0 = __builtin_nontemporal_load(
                            (const i32x4*)(rsl + (size_t)(t + 1) * 8192 + tid * 16));

                i32x4 acc[4];
#pragma unroll
                for (int n = 0; n < 4; ++n) acc[n] = (i32x4){0, 0, 0, 0};

                __builtin_amdgcn_s_setprio(1);
                i32x4 afc = *(const i32x4*)(bufr + l * 16);
#pragma unroll
                for (int ks = 0; ks < 8; ++ks) {
                    i32x4 afn;
                    if (ks < 7) afn = *(const i32x4*)(bufr + (ks + 1) * 1024 + l * 16);
                    if (ks < 4) {
#pragma unroll
                        for (int n = 0; n < 4; ++n)
                            acc[n] = __builtin_amdgcn_mfma_i32_16x16x64_i8(afc, WR[ks][n], acc[n], 0, 0, 0);
                    } else {
#pragma unroll
                        for (int n = 0; n < 4; ++n) {
                            const i32x4 bfr = *(const i32x4*)(WL + (((ks - 4) * 32 + wq * 4 + n) * 64 + l) * 16);
                            acc[n] = __builtin_amdgcn_mfma_i32_16x16x64_i8(afc, bfr, acc[n], 0, 0, 0);
                        }
                    }
                    afc = afn;
                }
                __builtin_amdgcn_s_setprio(0);

#pragma unroll
                for (int n = 0; n < 4; ++n) {
                    f32x4 zv;
#pragma unroll
                    for (int jr = 0; jr < 4; ++jr) zv[jr] = bv[n] + (float)acc[n][jr] * f[n];
                    __builtin_nontemporal_store(zv,
                        (f32x4*)(zsl + (size_t)t * 32768 + ((wq * 4 + n) * 64 + l) * 16));
                }

                if (pf) *(i32x4*)(bufw + tid * 16) = p0;   // stage next slab
                __syncthreads();   // single barrier: skew <=1 step, 3 slabs safe
            }

            if (tid == 0)
                __hip_atomic_store(&F[512 + g * 32 + c], 1, __ATOMIC_RELEASE, __HIP_MEMORY_SCOPE_AGENT);
        }
    }
}

// ---------------------------------------------------------------------------
// Batch-axis softmax stats per hidden column.
// ---------------------------------------------------------------------------
__global__ void colstats_kernel(const float* __restrict__ encoded,
                                float* __restrict__ colmax,
                                float* __restrict__ rsinv)
{
    const int h = blockIdx.x;
    const int lane = threadIdx.x;  // 64
    float v[4];
#pragma unroll
    for (int r = 0; r < 4; ++r) v[r] = encoded[(size_t)(lane + 64 * r) * NH + h];
    float mx = fmaxf(fmaxf(v[0], v[1]), fmaxf(v[2], v[3]));
#pragma unroll
    for (int s = 1; s < 64; s <<= 1) mx = fmaxf(mx, __shfl_xor(mx, s));
    float sum = 0.f;
#pragma unroll
    for (int r = 0; r < 4; ++r) sum += __expf(v[r] - mx);
#pragma unroll
    for (int s = 1; s < 64; s <<= 1) sum += __shfl_xor(sum, s);
    if (lane == 0) { colmax[h] = mx; rsinv[h] = 1.0f / sum; }
}

// ---------------------------------------------------------------------------
// Decoder: one batch element per thread; 4-dim recurrence in registers.
// ---------------------------------------------------------------------------
__global__ void decoder_kernel(
    const float* __restrict__ encoded,
    const float* __restrict__ colmax, const float* __restrict__ rsinv,
    const float* __restrict__ dWih0, const float* __restrict__ dWhh0,
    const float* __restrict__ dbih0, const float* __restrict__ dbhh0,
    const float* __restrict__ dWih1, const float* __restrict__ dWhh1,
    const float* __restrict__ dbih1, const float* __restrict__ dbhh1,
    float* __restrict__ out)
{
    const int b = blockIdx.x * 64 + threadIdx.x;

    float W0[16], Wi[16], W1[16];
#pragma unroll
    for (int e = 0; e < 16; ++e) { W0[e] = dWhh0[e]; Wi[e] = dWih1[e]; W1[e] = dWhh1[e]; }

    float c1[4], c2[4];
#pragma unroll
    for (int j = 0; j < 4; ++j) { c1[j] = dbih0[j] + dbhh0[j]; c2[j] = dbih1[j] + dbhh1[j]; }

    const float* er = encoded + (size_t)b * NH;
#pragma unroll 1
    for (int h = 0; h < NH; h += 4) {
        const float4 ev = *(const float4*)(er + h);
        const float4 cm = *(const float4*)(colmax + h);
        const float4 rs = *(const float4*)(rsinv + h);
        float p0 = __expf(ev.x - cm.x) * rs.x;
        float p1 = __expf(ev.y - cm.y) * rs.y;
        float p2 = __expf(ev.z - cm.z) * rs.z;
        float p3 = __expf(ev.w - cm.w) * rs.w;
#pragma unroll
        for (int j = 0; j < 4; ++j) {
            const float4 w = *(const float4*)(dWih0 + (size_t)j * NH + h);
            c1[j] += p0 * w.x + p1 * w.y + p2 * w.z + p3 * w.w;
        }
    }

    float h1[4] = {0.f, 0.f, 0.f, 0.f};
    float h2[4] = {0.f, 0.f, 0.f, 0.f};
    float* op = out + (size_t)b * NS * NV;

#pragma unroll 1
    for (int t = 0; t < NS; ++t) {
        float n1[4];
#pragma unroll
        for (int j = 0; j < 4; ++j)
            n1[j] = fast_tanh(c1[j] + W0[j*4+0]*h1[0] + W0[j*4+1]*h1[1]
                                    + W0[j*4+2]*h1[2] + W0[j*4+3]*h1[3]);
        float n2[4];
#pragma unroll
        for (int j = 0; j < 4; ++j)
            n2[j] = fast_tanh(c2[j] + Wi[j*4+0]*n1[0] + Wi[j*4+1]*n1[1]
                                    + Wi[j*4+2]*n1[2] + Wi[j*4+3]*n1[3]
                                    + W1[j*4+0]*h2[0] + W1[j*4+1]*h2[1]
                                    + W1[j*4+2]*h2[2] + W1[j*4+3]*h2[3]);
#pragma unroll
        for (int j = 0; j < 4; ++j) { h1[j] = n1[j]; h2[j] = n2[j]; }
        *(float4*)(op + (size_t)t * NV) = make_float4(n2[0], n2[1], n2[2], n2[3]);
    }
}

extern "C" void kernel_launch(void* const* d_in, const int* in_sizes, int n_in,
                              void* d_out, int out_size, void* d_ws, size_t ws_size,
                              hipStream_t stream)
{
    const float* x     = (const float*)d_in[0];
    const float* eWih0 = (const float*)d_in[1];
    const float* eWhh0 = (const float*)d_in[2];
    const float* ebih0 = (const float*)d_in[3];
    const float* ebhh0 = (const float*)d_in[4];
    const float* eWih1 = (const float*)d_in[5];
    const float* eWhh1 = (const float*)d_in[6];
    const float* ebih1 = (const float*)d_in[7];
    const float* ebhh1 = (const float*)d_in[8];
    const float* dWih0 = (const float*)d_in[9];
    const float* dWhh0 = (const float*)d_in[10];
    const float* dbih0 = (const float*)d_in[11];
    const float* dbhh0 = (const float*)d_in[12];
    const float* dWih1 = (const float*)d_in[13];
    const float* dWhh1 = (const float*)d_in[14];
    const float* dbih1 = (const float*)d_in[15];
    const float* dbhh1 = (const float*)d_in[16];

    char*  ws     = (char*)d_ws;
    float* enc    = (float*)(ws + ENC_OFF);
    float* colmax = (float*)(ws + CM_OFF);
    float* rsinv  = (float*)(ws + RS_OFF);

    hipFuncSetAttribute((const void*)persist_kernel,
                        hipFuncAttributeMaxDynamicSharedMemorySize, 155648);

    // zero flags
    hipMemsetAsync(d_ws, 0, 8192, stream);

    // one-shot weight quantization (i8 B-frags + per-col scales)
    prep_kernel<<<96, 256, 0, stream>>>(eWhh0, eWhh1, eWih1, ws);

    // persistent pipelined encoder (A, B, G roles — r14 sync graph)
    persist_kernel<<<48, 512, 155648, stream>>>(x, eWih0, ebih0, ebhh0,
                                                ebih1, ebhh1, ws);

    colstats_kernel<<<NH, 64, 0, stream>>>(enc, colmax, rsinv);
    decoder_kernel<<<4, 64, 0, stream>>>(enc, colmax, rsinv,
                                         dWih0, dWhh0, dbih0, dbhh0,
                                         dWih1, dWhh1, dbih1, dbhh1,
                                         (float*)d_out);
}

// Round 17
// 1650.579 us; speedup vs baseline: 1.1052x; 1.0329x over previous
//
#include <hip/hip_runtime.h>
#include <hip/hip_bf16.h>

#define NB 256   // batch
#define NS 512   // seq len
#define NV 4     // vocab
#define NH 512   // encoder hidden
#define CH 16    // steps per chunk
#define NCH 32   // chunks

typedef __bf16 bf16x8 __attribute__((ext_vector_type(8)));
typedef float  f32x4  __attribute__((ext_vector_type(4)));
typedef int    i32x4  __attribute__((ext_vector_type(4)));

// ---- workspace byte offsets ----
// flags 8KB | h1ring (i8) 4MB | zring (f32) 16MB | enc 512KB | cm/rs | frags_i8 3x256KB | scales 3x2KB
#define H1RING_OFF  8192
#define ZRING_OFF   (H1RING_OFF + (4u << 20))
#define ENC_OFF     (ZRING_OFF + (16u << 20))
#define CM_OFF      (ENC_OFF + NB*NH*4)
#define RS_OFF      (CM_OFF + 2048)
#define FRAG_OFF    (RS_OFF + 2048)
#define SCALE_OFF   (FRAG_OFF + 3*262144)

__device__ __forceinline__ float fast_tanh(float x) {
    x = fminf(12.0f, fmaxf(-12.0f, x));
    float e = __expf(2.0f * x);
    return (e - 1.0f) / (e + 1.0f);
}

__device__ __forceinline__ int aload(int* p) {
    return __hip_atomic_load(p, __ATOMIC_ACQUIRE, __HIP_MEMORY_SCOPE_AGENT);
}

// ---------------------------------------------------------------------------
// One-shot: quantize weight matrices to int8 MFMA B-fragments (16x16x64 i8)
// with per-column scales.  frag layout: ((ks64*32 + gt)*64 + l)*16 bytes;
// lane l byte j <-> W[col = gt*16 + (l&15)][k = ks64*64 + (l>>4)*16 + j].
// scales[mt*512+col] = colmax/(127*127)  (dequant: s = i32acc * f).
// ---------------------------------------------------------------------------
__global__ void prep_kernel(const float* __restrict__ W0, const float* __restrict__ W1,
                            const float* __restrict__ WG, char* __restrict__ ws)
{
    const int mt = blockIdx.x >> 5;     // 0=Whh0(A), 1=Whh1(B), 2=Wih1(G)
    const int gt = blockIdx.x & 31;
    const float* src = (mt == 0) ? W0 : (mt == 1) ? W1 : WG;
    char*  dst = ws + FRAG_OFF + (size_t)mt * 262144;
    float* fsc = (float*)(ws + SCALE_OFF) + mt * 512;
    const int tid = threadIdx.x;
    const int cg = tid >> 4, ti = tid & 15;

    __shared__ float cmax[16][17];
    __shared__ float inv[16];

    // per-column absmax (cols gt*16 .. +15)
    {
        const int col = gt * 16 + cg;
        float m = 0.f;
        for (int e = ti; e < NH; e += 16) m = fmaxf(m, fabsf(src[(size_t)col * NH + e]));
        cmax[cg][ti] = m;
    }
    __syncthreads();
    if (ti == 0) {
        float mm = 0.f;
#pragma unroll
        for (int j = 0; j < 16; ++j) mm = fmaxf(mm, cmax[cg][j]);
        inv[cg] = (mm > 0.f) ? 127.0f / mm : 0.f;
        fsc[gt * 16 + cg] = mm / (127.0f * 127.0f);
    }
    __syncthreads();

    for (int e = tid; e < 512; e += 256) {
        const int ks = e >> 6, l = e & 63;
        const int c16 = l & 15;
        const float iv = inv[c16];
        const float* p = src + (size_t)(gt * 16 + c16) * NH + ks * 64 + ((l >> 4) << 4);
        int vi[4];
#pragma unroll
        for (int w = 0; w < 4; ++w) {
            int b0 = __float2int_rn(p[w*4+0] * iv) & 255;
            int b1 = __float2int_rn(p[w*4+1] * iv) & 255;
            int b2 = __float2int_rn(p[w*4+2] * iv) & 255;
            int b3 = __float2int_rn(p[w*4+3] * iv) & 255;
            vi[w] = b0 | (b1 << 8) | (b2 << 16) | (b3 << 24);
        }
        *(i32x4*)(dst + ((size_t)(ks * 32 + gt) * 64 + l) * 16) = (i32x4){vi[0], vi[1], vi[2], vi[3]};
    }
}

// ---------------------------------------------------------------------------
// Persistent pipeline: 48 WGs x 512 threads, 1 block/CU.
// i8 weights = 256KB -> FULLY CU-RESIDENT:
//   ks64 0-3 in VGPR (WR[4][4] i32x4 = 64 regs/wave), ks64 4-7 in LDS (128KB),
//   h state as i8 (dbuf 2x8KB).  Zero per-step global weight traffic.
// Dequant: s = i32acc * f[col] (+ x-term bf16 MFMA / + z f32 / + bias).
// role A (blk 0-15): h1 chain. role B (16-31): h2 chain. role G (32-47): z.
// ---------------------------------------------------------------------------
extern "C" __global__ __launch_bounds__(512, 1)
void persist_kernel(const float* __restrict__ x,
                    const float* __restrict__ eWih0,
                    const float* __restrict__ ebih0, const float* __restrict__ ebhh0,
                    const float* __restrict__ ebih1, const float* __restrict__ ebhh1,
                    char* __restrict__ ws)
{
    extern __shared__ char lds[];
    int*   F      = (int*)ws;
    char*  h1ring = ws + H1RING_OFF;
    char*  zring  = ws + ZRING_OFF;
    float* enc    = (float*)(ws + ENC_OFF);

    const int blk  = blockIdx.x;
    const int role = blk >> 4;     // 0=A, 1=B, 2=G
    const int g    = blk & 15;
    const int tid  = threadIdx.x;
    const int wq   = tid >> 6;     // wave 0..7
    const int l    = tid & 63;
    const int lm   = l & 15;
    const int q    = l >> 4;

    const int mt = (role == 0) ? 0 : (role == 1) ? 1 : 2;
    const char*  frag = ws + FRAG_OFF + (size_t)mt * 262144;
    const float* fsc  = (const float*)(ws + SCALE_OFF) + mt * 512;

    char* HS = lds;            // [0,16384) h_i8 double buffer (2 x 8KB)
    char* WL = lds + 16384;    // [16384,147456) ks64 4..7 i8 slabs (4 x 32KB)

    // ---- weights: ks64 0-3 resident in VGPR, ks64 4-7 into LDS ----
    i32x4 WR[4][4];
#pragma unroll
    for (int ks = 0; ks < 4; ++ks)
#pragma unroll
        for (int n = 0; n < 4; ++n)
            WR[ks][n] = *(const i32x4*)(frag + ((size_t)(ks * 32 + wq * 4 + n) * 64 + l) * 16);
#pragma unroll
    for (int ks = 4; ks < 8; ++ks)
#pragma unroll
        for (int n = 0; n < 4; ++n) {
            const i32x4 v = *(const i32x4*)(frag + ((size_t)(ks * 32 + wq * 4 + n) * 64 + l) * 16);
            *(i32x4*)(WL + (((ks - 4) * 32 + wq * 4 + n) * 64 + l) * 16) = v;
        }
    float f[4];
#pragma unroll
    for (int n = 0; n < 4; ++n) f[n] = fsc[wq * 64 + n * 16 + lm];

    if (role <= 1) {
        // ================= chain roles (A: layer-0, B: layer-1) =================
        const bool isA = (role == 0);

        // zero h_i8 state (both buffers)
        {
            for (int o = tid; o < 512; o += 512) *(f32x4*)(HS + o * 32) = (f32x4){0.f,0.f,0.f,0.f};
            *(f32x4*)(HS + tid * 32 + 16) = (f32x4){0.f,0.f,0.f,0.f};
        }

        bf16x8 EB[4];
        float  bias[4];
#pragma unroll
        for (int n = 0; n < 4; ++n) {
            const int col = wq * 64 + n * 16 + lm;
#pragma unroll
            for (int j = 0; j < 8; ++j) EB[n][j] = (__bf16)0.f;
            if (isA) {
                if (q == 0) {
                    const float4 w0 = *(const float4*)(eWih0 + (size_t)col * NV);
                    EB[n][0] = (__bf16)w0.x; EB[n][1] = (__bf16)w0.y;
                    EB[n][2] = (__bf16)w0.z; EB[n][3] = (__bf16)w0.w;
                }
                bias[n] = ebih0[col] + ebhh0[col];
            } else {
                bias[n] = 0.f;  // z already contains layer-1 biases
            }
        }
        __syncthreads();

#pragma unroll 1
        for (int c = 0; c < NCH; ++c) {
            // ---- chunk-entry sync ----
            if (isA) {
                if (c >= 2) {   // backpressure: G consumed h1 chunk c-2 (same parity)
                    if (tid == 0)
                        while (aload(&F[512 + g * 32 + (c - 2)]) < 1)
                            __builtin_amdgcn_s_sleep(2);
                    __syncthreads();
                }
            } else {
                if (tid == 0)
                    while (aload(&F[512 + g * 32 + c]) < 1)
                        __builtin_amdgcn_s_sleep(2);
                __syncthreads();
                __builtin_amdgcn_fence(__ATOMIC_ACQUIRE, "agent");
            }

            char* rsl = h1ring + (size_t)((g * 2 + (c & 1)) * CH) * 8192;   // A writes (i8)
            char* zsl = zring  + (size_t)((g * 2 + (c & 1)) * CH) * 32768;  // B reads (f32)

            f32x4 zn[4];
            if (!isA) {
#pragma unroll
                for (int n = 0; n < 4; ++n)
                    zn[n] = __builtin_nontemporal_load(
                        (const f32x4*)(zsl + ((wq * 4 + n) * 64 + l) * 16));
            }

#pragma unroll 1
            for (int t = 0; t < CH; ++t) {
                const int i  = c * CH + t;
                const int rb = t & 1;
                const char* hsr = HS + rb * 8192;
                char*       hsw = HS + (rb ^ 1) * 8192;

                i32x4 acc[4];
#pragma unroll
                for (int n = 0; n < 4; ++n) acc[n] = (i32x4){0, 0, 0, 0};
                f32x4 xacc[4];
                bf16x8 xa;
                if (isA) {
#pragma unroll
                    for (int n = 0; n < 4; ++n)
                        xacc[n] = (f32x4){bias[n], bias[n], bias[n], bias[n]};
                    const float4 xv = *(const float4*)(x + ((size_t)(g * 16 + lm) * NS + i) * NV);
#pragma unroll
                    for (int j = 0; j < 8; ++j) xa[j] = (__bf16)0.f;
                    if (q == 0) {
                        xa[0] = (__bf16)xv.x; xa[1] = (__bf16)xv.y;
                        xa[2] = (__bf16)xv.z; xa[3] = (__bf16)xv.w;
                    }
#pragma unroll
                    for (int n = 0; n < 4; ++n)
                        xacc[n] = __builtin_amdgcn_mfma_f32_16x16x32_bf16(xa, EB[n], xacc[n], 0, 0, 0);
                } else {
#pragma unroll
                    for (int n = 0; n < 4; ++n) xacc[n] = zn[n];
                    if (t + 1 < CH) {
#pragma unroll
                        for (int n = 0; n < 4; ++n)
                            zn[n] = __builtin_nontemporal_load(
                                (const f32x4*)(zsl + (size_t)(t + 1) * 32768 +
                                               ((wq * 4 + n) * 64 + l) * 16));
                    }
                }

                // ---- K-steps: 4 resident + 4 LDS, K=64 each ----
#pragma unroll
                for (int ks = 0; ks < 4; ++ks) {
                    const i32x4 af = *(const i32x4*)(hsr + ks * 1024 + l * 16);
#pragma unroll
                    for (int n = 0; n < 4; ++n)
                        acc[n] = __builtin_amdgcn_mfma_i32_16x16x64_i8(af, WR[ks][n], acc[n], 0, 0, 0);
                }
#pragma unroll
                for (int ks = 4; ks < 8; ++ks) {
                    const i32x4 af = *(const i32x4*)(hsr + ks * 1024 + l * 16);
#pragma unroll
                    for (int n = 0; n < 4; ++n) {
                        const i32x4 bfr = *(const i32x4*)(WL + (((ks - 4) * 32 + wq * 4 + n) * 64 + l) * 16);
                        acc[n] = __builtin_amdgcn_mfma_i32_16x16x64_i8(af, bfr, acc[n], 0, 0, 0);
                    }
                }

                // ---- dequant + epilogue ----
                if (!isA && i == NS - 1) {
                    // encoded = PRE-tanh (arctanh(tanh(s)) == s)
#pragma unroll
                    for (int n = 0; n < 4; ++n) {
                        const int col = wq * 64 + n * 16 + lm;
#pragma unroll
                        for (int jr = 0; jr < 4; ++jr)
                            enc[(size_t)(g * 16 + q * 4 + jr) * NH + col] =
                                xacc[n][jr] + (float)acc[n][jr] * f[n];
                    }
                } else {
#pragma unroll
                    for (int n = 0; n < 4; ++n) {
#pragma unroll
                        for (int jr = 0; jr < 4; ++jr) {
                            const float s  = xacc[n][jr] + (float)acc[n][jr] * f[n];
                            const float th = fast_tanh(s);
                            const int slot = (q * 4 + jr) | (n << 4);
                            *(char*)(hsw + wq * 1024 + slot * 16 + lm) =
                                (char)__float2int_rn(th * 127.0f);
                        }
                    }
                }
                __syncthreads();  // hsw complete for all waves

                if (isA) {
                    // copy new h1_i8 (8 KB) -> h1ring, NT
                    const i32x4 v = *(const i32x4*)(hsw + tid * 16);
                    __builtin_nontemporal_store(v, (i32x4*)(rsl + (size_t)t * 8192 + tid * 16));
                }
            }

            // ---- chunk-exit publish ----
            __syncthreads();
            if (tid == 0) {
                if (isA)
                    __hip_atomic_store(&F[g * 16], c + 1, __ATOMIC_RELEASE, __HIP_MEMORY_SCOPE_AGENT);
                else
                    __hip_atomic_store(&F[256 + g * 16], c + 1, __ATOMIC_RELEASE, __HIP_MEMORY_SCOPE_AGENT);
            }
        }
    } else {
        // ================= G role: z[c] = h1[c] @ Wih1^T + bias =================
        float bv[4];
#pragma unroll
        for (int n = 0; n < 4; ++n) {
            const int col = wq * 64 + n * 16 + lm;
            bv[n] = ebih1[col] + ebhh1[col];
        }
        __syncthreads();

#pragma unroll 1
        for (int c = 0; c < NCH; ++c) {
            if (tid == 0) {
                while (aload(&F[g * 16]) < c + 1) __builtin_amdgcn_s_sleep(2);
                if (c >= 2)
                    while (aload(&F[256 + g * 16]) < c - 1) __builtin_amdgcn_s_sleep(2);
            }
            __syncthreads();
            __builtin_amdgcn_fence(__ATOMIC_ACQUIRE, "agent");

            const char* rsl = h1ring + (size_t)((g * 2 + (c & 1)) * CH) * 8192;
            char*       zsl = zring  + (size_t)((g * 2 + (c & 1)) * CH) * 32768;

            // stage t=0 (16 B/thread, 8 KB slab)
            *(i32x4*)(HS + tid * 16) =
                __builtin_nontemporal_load((const i32x4*)(rsl + tid * 16));
            __syncthreads();

#pragma unroll 1
            for (int t = 0; t < CH; ++t) {
                const char* bufr = HS + (t & 1) * 8192;
                char*       bufw = HS + ((t + 1) & 1) * 8192;
                i32x4 p0;
                const bool pf = (t + 1 < CH);
                if (pf) p0 = __builtin_nontemporal_load(
                            (const i32x4*)(rsl + (size_t)(t + 1) * 8192 + tid * 16));

                i32x4 acc[4];
#pragma unroll
                for (int n = 0; n < 4; ++n) acc[n] = (i32x4){0, 0, 0, 0};
#pragma unroll
                for (int ks = 0; ks < 4; ++ks) {
                    const i32x4 af = *(const i32x4*)(bufr + ks * 1024 + l * 16);
#pragma unroll
                    for (int n = 0; n < 4; ++n)
                        acc[n] = __builtin_amdgcn_mfma_i32_16x16x64_i8(af, WR[ks][n], acc[n], 0, 0, 0);
                }
#pragma unroll
                for (int ks = 4; ks < 8; ++ks) {
                    const i32x4 af = *(const i32x4*)(bufr + ks * 1024 + l * 16);
#pragma unroll
                    for (int n = 0; n < 4; ++n) {
                        const i32x4 bfr = *(const i32x4*)(WL + (((ks - 4) * 32 + wq * 4 + n) * 64 + l) * 16);
                        acc[n] = __builtin_amdgcn_mfma_i32_16x16x64_i8(af, bfr, acc[n], 0, 0, 0);
                    }
                }
#pragma unroll
                for (int n = 0; n < 4; ++n) {
                    f32x4 zv;
#pragma unroll
                    for (int jr = 0; jr < 4; ++jr) zv[jr] = bv[n] + (float)acc[n][jr] * f[n];
                    __builtin_nontemporal_store(zv,
                        (f32x4*)(zsl + (size_t)t * 32768 + ((wq * 4 + n) * 64 + l) * 16));
                }

                __syncthreads();            // everyone done reading bufw's old data
                if (pf) *(i32x4*)(bufw + tid * 16) = p0;
                __syncthreads();            // staged slab visible
            }

            __syncthreads();
            if (tid == 0)
                __hip_atomic_store(&F[512 + g * 32 + c], 1, __ATOMIC_RELEASE, __HIP_MEMORY_SCOPE_AGENT);
        }
    }
}

// ---------------------------------------------------------------------------
// Batch-axis softmax stats per hidden column.
// ---------------------------------------------------------------------------
__global__ void colstats_kernel(const float* __restrict__ encoded,
                                float* __restrict__ colmax,
                                float* __restrict__ rsinv)
{
    const int h = blockIdx.x;
    const int lane = threadIdx.x;  // 64
    float v[4];
#pragma unroll
    for (int r = 0; r < 4; ++r) v[r] = encoded[(size_t)(lane + 64 * r) * NH + h];
    float mx = fmaxf(fmaxf(v[0], v[1]), fmaxf(v[2], v[3]));
#pragma unroll
    for (int s = 1; s < 64; s <<= 1) mx = fmaxf(mx, __shfl_xor(mx, s));
    float sum = 0.f;
#pragma unroll
    for (int r = 0; r < 4; ++r) sum += __expf(v[r] - mx);
#pragma unroll
    for (int s = 1; s < 64; s <<= 1) sum += __shfl_xor(sum, s);
    if (lane == 0) { colmax[h] = mx; rsinv[h] = 1.0f / sum; }
}

// ---------------------------------------------------------------------------
// Decoder: one batch element per thread; 4-dim recurrence in registers.
// ---------------------------------------------------------------------------
__global__ void decoder_kernel(
    const float* __restrict__ encoded,
    const float* __restrict__ colmax, const float* __restrict__ rsinv,
    const float* __restrict__ dWih0, const float* __restrict__ dWhh0,
    const float* __restrict__ dbih0, const float* __restrict__ dbhh0,
    const float* __restrict__ dWih1, const float* __restrict__ dWhh1,
    const float* __restrict__ dbih1, const float* __restrict__ dbhh1,
    float* __restrict__ out)
{
    const int b = blockIdx.x * 64 + threadIdx.x;

    float W0[16], Wi[16], W1[16];
#pragma unroll
    for (int e = 0; e < 16; ++e) { W0[e] = dWhh0[e]; Wi[e] = dWih1[e]; W1[e] = dWhh1[e]; }

    float c1[4], c2[4];
#pragma unroll
    for (int j = 0; j < 4; ++j) { c1[j] = dbih0[j] + dbhh0[j]; c2[j] = dbih1[j] + dbhh1[j]; }

    const float* er = encoded + (size_t)b * NH;
#pragma unroll 1
    for (int h = 0; h < NH; h += 4) {
        const float4 ev = *(const float4*)(er + h);
        const float4 cm = *(const float4*)(colmax + h);
        const float4 rs = *(const float4*)(rsinv + h);
        float p0 = __expf(ev.x - cm.x) * rs.x;
        float p1 = __expf(ev.y - cm.y) * rs.y;
        float p2 = __expf(ev.z - cm.z) * rs.z;
        float p3 = __expf(ev.w - cm.w) * rs.w;
#pragma unroll
        for (int j = 0; j < 4; ++j) {
            const float4 w = *(const float4*)(dWih0 + (size_t)j * NH + h);
            c1[j] += p0 * w.x + p1 * w.y + p2 * w.z + p3 * w.w;
        }
    }

    float h1[4] = {0.f, 0.f, 0.f, 0.f};
    float h2[4] = {0.f, 0.f, 0.f, 0.f};
    float* op = out + (size_t)b * NS * NV;

#pragma unroll 1
    for (int t = 0; t < NS; ++t) {
        float n1[4];
#pragma unroll
        for (int j = 0; j < 4; ++j)
            n1[j] = fast_tanh(c1[j] + W0[j*4+0]*h1[0] + W0[j*4+1]*h1[1]
                                    + W0[j*4+2]*h1[2] + W0[j*4+3]*h1[3]);
        float n2[4];
#pragma unroll
        for (int j = 0; j < 4; ++j)
            n2[j] = fast_tanh(c2[j] + Wi[j*4+0]*n1[0] + Wi[j*4+1]*n1[1]
                                    + Wi[j*4+2]*n1[2] + Wi[j*4+3]*n1[3]
                                    + W1[j*4+0]*h2[0] + W1[j*4+1]*h2[1]
                                    + W1[j*4+2]*h2[2] + W1[j*4+3]*h2[3]);
#pragma unroll
        for (int j = 0; j < 4; ++j) { h1[j] = n1[j]; h2[j] = n2[j]; }
        *(float4*)(op + (size_t)t * NV) = make_float4(n2[0], n2[1], n2[2], n2[3]);
    }
}

extern "C" void kernel_launch(void* const* d_in, const int* in_sizes, int n_in,
                              void* d_out, int out_size, void* d_ws, size_t ws_size,
                              hipStream_t stream)
{
    const float* x     = (const float*)d_in[0];
    const float* eWih0 = (const float*)d_in[1];
    const float* eWhh0 = (const float*)d_in[2];
    const float* ebih0 = (const float*)d_in[3];
    const float* ebhh0 = (const float*)d_in[4];
    const float* eWih1 = (const float*)d_in[5];
    const float* eWhh1 = (const float*)d_in[6];
    const float* ebih1 = (const float*)d_in[7];
    const float* ebhh1 = (const float*)d_in[8];
    const float* dWih0 = (const float*)d_in[9];
    const float* dWhh0 = (const float*)d_in[10];
    const float* dbih0 = (const float*)d_in[11];
    const float* dbhh0 = (const float*)d_in[12];
    const float* dWih1 = (const float*)d_in[13];
    const float* dWhh1 = (const float*)d_in[14];
    const float* dbih1 = (const float*)d_in[15];
    const float* dbhh1 = (const float*)d_in[16];

    char*  ws     = (char*)d_ws;
    float* enc    = (float*)(ws + ENC_OFF);
    float* colmax = (float*)(ws + CM_OFF);
    float* rsinv  = (float*)(ws + RS_OFF);

    hipFuncSetAttribute((const void*)persist_kernel,
                        hipFuncAttributeMaxDynamicSharedMemorySize, 147456);

    // zero flags
    hipMemsetAsync(d_ws, 0, 4096, stream);

    // one-shot weight quantization (i8 B-frags + per-col scales)
    prep_kernel<<<96, 256, 0, stream>>>(eWhh0, eWhh1, eWih1, ws);

    // persistent pipelined encoder (i8 weights fully CU-resident)
    persist_kernel<<<48, 512, 147456, stream>>>(x, eWih0, ebih0, ebhh0,
                                                ebih1, ebhh1, ws);

    colstats_kernel<<<NH, 64, 0, stream>>>(enc, colmax, rsinv);
    decoder_kernel<<<4, 64, 0, stream>>>(enc, colmax, rsinv,
                                         dWih0, dWhh0, dbih0, dbhh0,
                                         dWih1, dWhh1, dbih1, dbhh1,
                                         (float*)d_out);
}

// Round 18
// 1624.536 us; speedup vs baseline: 1.1230x; 1.0160x over previous
//
#include <hip/hip_runtime.h>
#include <hip/hip_bf16.h>

#define NB 256   // batch
#define NS 512   // seq len
#define NV 4     // vocab
#define NH 512   // encoder hidden
#define CH 16    // steps per chunk
#define NCH 32   // chunks

typedef __bf16 bf16x8 __attribute__((ext_vector_type(8)));
typedef float  f32x4  __attribute__((ext_vector_type(4)));
typedef int    i32x4  __attribute__((ext_vector_type(4)));

// ---- workspace byte offsets ----
// flags 8KB | h1ring (i8) 4MB | zring (f32) 16MB | enc 512KB | cm/rs | frags_i8 3x256KB | scales 3x2KB
#define H1RING_OFF  8192
#define ZRING_OFF   (H1RING_OFF + (4u << 20))
#define ENC_OFF     (ZRING_OFF + (16u << 20))
#define CM_OFF      (ENC_OFF + NB*NH*4)
#define RS_OFF      (CM_OFF + 2048)
#define FRAG_OFF    (RS_OFF + 2048)
#define SCALE_OFF   (FRAG_OFF + 3*262144)

// tanh(x) = 1 - 2/(e^{2x}+1).  Clamp-free: e^inf -> 2/inf = 0 -> +1;
// e^-inf -> 0 -> 1-2 = -1.  ~5 VALU ops (mul, exp, add, rcp, fma).
__device__ __forceinline__ float fast_tanh(float x) {
    const float e = __expf(2.0f * x);
    return 1.0f - 2.0f * __frcp_rn(e + 1.0f);
}

__device__ __forceinline__ int aload(int* p) {
    return __hip_atomic_load(p, __ATOMIC_ACQUIRE, __HIP_MEMORY_SCOPE_AGENT);
}

// ---------------------------------------------------------------------------
// One-shot: quantize weight matrices to int8 MFMA B-fragments (16x16x64 i8)
// with per-column scales.  frag layout: ((ks64*32 + gt)*64 + l)*16 bytes;
// lane l byte j <-> W[col = gt*16 + (l&15)][k = ks64*64 + (l>>4)*16 + j].
// scales[mt*512+col] = colmax/(127*127)  (dequant: s = i32acc * f).
// ---------------------------------------------------------------------------
__global__ void prep_kernel(const float* __restrict__ W0, const float* __restrict__ W1,
                            const float* __restrict__ WG, char* __restrict__ ws)
{
    const int mt = blockIdx.x >> 5;     // 0=Whh0(A), 1=Whh1(B), 2=Wih1(G)
    const int gt = blockIdx.x & 31;
    const float* src = (mt == 0) ? W0 : (mt == 1) ? W1 : WG;
    char*  dst = ws + FRAG_OFF + (size_t)mt * 262144;
    float* fsc = (float*)(ws + SCALE_OFF) + mt * 512;
    const int tid = threadIdx.x;
    const int cg = tid >> 4, ti = tid & 15;

    __shared__ float cmax[16][17];
    __shared__ float inv[16];

    // per-column absmax (cols gt*16 .. +15)
    {
        const int col = gt * 16 + cg;
        float m = 0.f;
        for (int e = ti; e < NH; e += 16) m = fmaxf(m, fabsf(src[(size_t)col * NH + e]));
        cmax[cg][ti] = m;
    }
    __syncthreads();
    if (ti == 0) {
        float mm = 0.f;
#pragma unroll
        for (int j = 0; j < 16; ++j) mm = fmaxf(mm, cmax[cg][j]);
        inv[cg] = (mm > 0.f) ? 127.0f / mm : 0.f;
        fsc[gt * 16 + cg] = mm / (127.0f * 127.0f);
    }
    __syncthreads();

    for (int e = tid; e < 512; e += 256) {
        const int ks = e >> 6, l = e & 63;
        const int c16 = l & 15;
        const float iv = inv[c16];
        const float* p = src + (size_t)(gt * 16 + c16) * NH + ks * 64 + ((l >> 4) << 4);
        int vi[4];
#pragma unroll
        for (int w = 0; w < 4; ++w) {
            int b0 = __float2int_rn(p[w*4+0] * iv) & 255;
            int b1 = __float2int_rn(p[w*4+1] * iv) & 255;
            int b2 = __float2int_rn(p[w*4+2] * iv) & 255;
            int b3 = __float2int_rn(p[w*4+3] * iv) & 255;
            vi[w] = b0 | (b1 << 8) | (b2 << 16) | (b3 << 24);
        }
        *(i32x4*)(dst + ((size_t)(ks * 32 + gt) * 64 + l) * 16) = (i32x4){vi[0], vi[1], vi[2], vi[3]};
    }
}

// ---------------------------------------------------------------------------
// Persistent pipeline: 48 WGs x 512 threads, 1 block/CU.
// i8 weights = 256KB -> FULLY CU-RESIDENT:
//   ks64 0-3 in VGPR (WR[4][4] i32x4 = 64 regs/wave), ks64 4-7 in LDS (128KB),
//   h state as i8 (dbuf 2x8KB).  Zero per-step global weight traffic.
// Dequant: s = i32acc * f[col] (+ x-term bf16 MFMA / + z f32 / + bias).
// r18: clamp-free 5-op tanh; A prefetches next x float4 one step ahead.
// role A (blk 0-15): h1 chain. role B (16-31): h2 chain. role G (32-47): z.
// ---------------------------------------------------------------------------
extern "C" __global__ __launch_bounds__(512, 1)
void persist_kernel(const float* __restrict__ x,
                    const float* __restrict__ eWih0,
                    const float* __restrict__ ebih0, const float* __restrict__ ebhh0,
                    const float* __restrict__ ebih1, const float* __restrict__ ebhh1,
                    char* __restrict__ ws)
{
    extern __shared__ char lds[];
    int*   F      = (int*)ws;
    char*  h1ring = ws + H1RING_OFF;
    char*  zring  = ws + ZRING_OFF;
    float* enc    = (float*)(ws + ENC_OFF);

    const int blk  = blockIdx.x;
    const int role = blk >> 4;     // 0=A, 1=B, 2=G
    const int g    = blk & 15;
    const int tid  = threadIdx.x;
    const int wq   = tid >> 6;     // wave 0..7
    const int l    = tid & 63;
    const int lm   = l & 15;
    const int q    = l >> 4;

    const int mt = (role == 0) ? 0 : (role == 1) ? 1 : 2;
    const char*  frag = ws + FRAG_OFF + (size_t)mt * 262144;
    const float* fsc  = (const float*)(ws + SCALE_OFF) + mt * 512;

    char* HS = lds;            // [0,16384) h_i8 double buffer (2 x 8KB)
    char* WL = lds + 16384;    // [16384,147456) ks64 4..7 i8 slabs (4 x 32KB)

    // ---- weights: ks64 0-3 resident in VGPR, ks64 4-7 into LDS ----
    i32x4 WR[4][4];
#pragma unroll
    for (int ks = 0; ks < 4; ++ks)
#pragma unroll
        for (int n = 0; n < 4; ++n)
            WR[ks][n] = *(const i32x4*)(frag + ((size_t)(ks * 32 + wq * 4 + n) * 64 + l) * 16);
#pragma unroll
    for (int ks = 4; ks < 8; ++ks)
#pragma unroll
        for (int n = 0; n < 4; ++n) {
            const i32x4 v = *(const i32x4*)(frag + ((size_t)(ks * 32 + wq * 4 + n) * 64 + l) * 16);
            *(i32x4*)(WL + (((ks - 4) * 32 + wq * 4 + n) * 64 + l) * 16) = v;
        }
    float f[4];
#pragma unroll
    for (int n = 0; n < 4; ++n) f[n] = fsc[wq * 64 + n * 16 + lm];

    if (role <= 1) {
        // ================= chain roles (A: layer-0, B: layer-1) =================
        const bool isA = (role == 0);

        // zero h_i8 state (both buffers)
        {
            for (int o = tid; o < 512; o += 512) *(f32x4*)(HS + o * 32) = (f32x4){0.f,0.f,0.f,0.f};
            *(f32x4*)(HS + tid * 32 + 16) = (f32x4){0.f,0.f,0.f,0.f};
        }

        bf16x8 EB[4];
        float  bias[4];
#pragma unroll
        for (int n = 0; n < 4; ++n) {
            const int col = wq * 64 + n * 16 + lm;
#pragma unroll
            for (int j = 0; j < 8; ++j) EB[n][j] = (__bf16)0.f;
            if (isA) {
                if (q == 0) {
                    const float4 w0 = *(const float4*)(eWih0 + (size_t)col * NV);
                    EB[n][0] = (__bf16)w0.x; EB[n][1] = (__bf16)w0.y;
                    EB[n][2] = (__bf16)w0.z; EB[n][3] = (__bf16)w0.w;
                }
                bias[n] = ebih0[col] + ebhh0[col];
            } else {
                bias[n] = 0.f;  // z already contains layer-1 biases
            }
        }
        __syncthreads();

        const float* xrow = x + (size_t)(g * 16 + lm) * NS * NV;   // A's x row base

#pragma unroll 1
        for (int c = 0; c < NCH; ++c) {
            // ---- chunk-entry sync ----
            if (isA) {
                if (c >= 2) {   // backpressure: G consumed h1 chunk c-2 (same parity)
                    if (tid == 0)
                        while (aload(&F[512 + g * 32 + (c - 2)]) < 1)
                            __builtin_amdgcn_s_sleep(2);
                    __syncthreads();
                }
            } else {
                if (tid == 0)
                    while (aload(&F[512 + g * 32 + c]) < 1)
                        __builtin_amdgcn_s_sleep(2);
                __syncthreads();
                __builtin_amdgcn_fence(__ATOMIC_ACQUIRE, "agent");
            }

            char* rsl = h1ring + (size_t)((g * 2 + (c & 1)) * CH) * 8192;   // A writes (i8)
            char* zsl = zring  + (size_t)((g * 2 + (c & 1)) * CH) * 32768;  // B reads (f32)

            f32x4 zn[4];
            float4 xv;
            if (isA) {
                xv = *(const float4*)(xrow + (size_t)(c * CH) * NV);        // prefetch t=0
            } else {
#pragma unroll
                for (int n = 0; n < 4; ++n)
                    zn[n] = __builtin_nontemporal_load(
                        (const f32x4*)(zsl + ((wq * 4 + n) * 64 + l) * 16));
            }

#pragma unroll 1
            for (int t = 0; t < CH; ++t) {
                const int i  = c * CH + t;
                const int rb = t & 1;
                const char* hsr = HS + rb * 8192;
                char*       hsw = HS + (rb ^ 1) * 8192;

                i32x4 acc[4];
#pragma unroll
                for (int n = 0; n < 4; ++n) acc[n] = (i32x4){0, 0, 0, 0};
                f32x4 xacc[4];
                bf16x8 xa;
                if (isA) {
#pragma unroll
                    for (int n = 0; n < 4; ++n)
                        xacc[n] = (f32x4){bias[n], bias[n], bias[n], bias[n]};
#pragma unroll
                    for (int j = 0; j < 8; ++j) xa[j] = (__bf16)0.f;
                    if (q == 0) {
                        xa[0] = (__bf16)xv.x; xa[1] = (__bf16)xv.y;
                        xa[2] = (__bf16)xv.z; xa[3] = (__bf16)xv.w;
                    }
                    if (t + 1 < CH)                                       // prefetch next x
                        xv = *(const float4*)(xrow + (size_t)(i + 1) * NV);
#pragma unroll
                    for (int n = 0; n < 4; ++n)
                        xacc[n] = __builtin_amdgcn_mfma_f32_16x16x32_bf16(xa, EB[n], xacc[n], 0, 0, 0);
                } else {
#pragma unroll
                    for (int n = 0; n < 4; ++n) xacc[n] = zn[n];
                    if (t + 1 < CH) {
#pragma unroll
                        for (int n = 0; n < 4; ++n)
                            zn[n] = __builtin_nontemporal_load(
                                (const f32x4*)(zsl + (size_t)(t + 1) * 32768 +
                                               ((wq * 4 + n) * 64 + l) * 16));
                    }
                }

                // ---- K-steps: 4 resident + 4 LDS, K=64 each ----
#pragma unroll
                for (int ks = 0; ks < 4; ++ks) {
                    const i32x4 af = *(const i32x4*)(hsr + ks * 1024 + l * 16);
#pragma unroll
                    for (int n = 0; n < 4; ++n)
                        acc[n] = __builtin_amdgcn_mfma_i32_16x16x64_i8(af, WR[ks][n], acc[n], 0, 0, 0);
                }
#pragma unroll
                for (int ks = 4; ks < 8; ++ks) {
                    const i32x4 af = *(const i32x4*)(hsr + ks * 1024 + l * 16);
#pragma unroll
                    for (int n = 0; n < 4; ++n) {
                        const i32x4 bfr = *(const i32x4*)(WL + (((ks - 4) * 32 + wq * 4 + n) * 64 + l) * 16);
                        acc[n] = __builtin_amdgcn_mfma_i32_16x16x64_i8(af, bfr, acc[n], 0, 0, 0);
                    }
                }

                // ---- dequant + epilogue ----
                if (!isA && i == NS - 1) {
                    // encoded = PRE-tanh (arctanh(tanh(s)) == s)
#pragma unroll
                    for (int n = 0; n < 4; ++n) {
                        const int col = wq * 64 + n * 16 + lm;
#pragma unroll
                        for (int jr = 0; jr < 4; ++jr)
                            enc[(size_t)(g * 16 + q * 4 + jr) * NH + col] =
                                xacc[n][jr] + (float)acc[n][jr] * f[n];
                    }
                } else {
#pragma unroll
                    for (int n = 0; n < 4; ++n) {
#pragma unroll
                        for (int jr = 0; jr < 4; ++jr) {
                            const float s  = xacc[n][jr] + (float)acc[n][jr] * f[n];
                            const float th = fast_tanh(s);
                            const int slot = (q * 4 + jr) | (n << 4);
                            *(char*)(hsw + wq * 1024 + slot * 16 + lm) =
                                (char)__float2int_rn(th * 127.0f);
                        }
                    }
                }
                __syncthreads();  // hsw complete for all waves

                if (isA) {
                    // copy new h1_i8 (8 KB) -> h1ring, NT
                    const i32x4 v = *(const i32x4*)(hsw + tid * 16);
                    __builtin_nontemporal_store(v, (i32x4*)(rsl + (size_t)t * 8192 + tid * 16));
                }
            }

            // ---- chunk-exit publish ----
            __syncthreads();
            if (tid == 0) {
                if (isA)
                    __hip_atomic_store(&F[g * 16], c + 1, __ATOMIC_RELEASE, __HIP_MEMORY_SCOPE_AGENT);
                else
                    __hip_atomic_store(&F[256 + g * 16], c + 1, __ATOMIC_RELEASE, __HIP_MEMORY_SCOPE_AGENT);
            }
        }
    } else {
        // ================= G role: z[c] = h1[c] @ Wih1^T + bias =================
        float bv[4];
#pragma unroll
        for (int n = 0; n < 4; ++n) {
            const int col = wq * 64 + n * 16 + lm;
            bv[n] = ebih1[col] + ebhh1[col];
        }
        __syncthreads();

#pragma unroll 1
        for (int c = 0; c < NCH; ++c) {
            if (tid == 0) {
                while (aload(&F[g * 16]) < c + 1) __builtin_amdgcn_s_sleep(2);
                if (c >= 2)
                    while (aload(&F[256 + g * 16]) < c - 1) __builtin_amdgcn_s_sleep(2);
            }
            __syncthreads();
            __builtin_amdgcn_fence(__ATOMIC_ACQUIRE, "agent");

            const char* rsl = h1ring + (size_t)((g * 2 + (c & 1)) * CH) * 8192;
            char*       zsl = zring  + (size_t)((g * 2 + (c & 1)) * CH) * 32768;

            // stage t=0 (16 B/thread, 8 KB slab)
            *(i32x4*)(HS + tid * 16) =
                __builtin_nontemporal_load((const i32x4*)(rsl + tid * 16));
            __syncthreads();

#pragma unroll 1
            for (int t = 0; t < CH; ++t) {
                const char* bufr = HS + (t & 1) * 8192;
                char*       bufw = HS + ((t + 1) & 1) * 8192;
                i32x4 p0;
                const bool pf = (t + 1 < CH);
                if (pf) p0 = __builtin_nontemporal_load(
                            (const i32x4*)(rsl + (size_t)(t + 1) * 8192 + tid * 16));

                i32x4 acc[4];
#pragma unroll
                for (int n = 0; n < 4; ++n) acc[n] = (i32x4){0, 0, 0, 0};
#pragma unroll
                for (int ks = 0; ks < 4; ++ks) {
                    const i32x4 af = *(const i32x4*)(bufr + ks * 1024 + l * 16);
#pragma unroll
                    for (int n = 0; n < 4; ++n)
                        acc[n] = __builtin_amdgcn_mfma_i32_16x16x64_i8(af, WR[ks][n], acc[n], 0, 0, 0);
                }
#pragma unroll
                for (int ks = 4; ks < 8; ++ks) {
                    const i32x4 af = *(const i32x4*)(bufr + ks * 1024 + l * 16);
#pragma unroll
                    for (int n = 0; n < 4; ++n) {
                        const i32x4 bfr = *(const i32x4*)(WL + (((ks - 4) * 32 + wq * 4 + n) * 64 + l) * 16);
                        acc[n] = __builtin_amdgcn_mfma_i32_16x16x64_i8(af, bfr, acc[n], 0, 0, 0);
                    }
                }
#pragma unroll
                for (int n = 0; n < 4; ++n) {
                    f32x4 zv;
#pragma unroll
                    for (int jr = 0; jr < 4; ++jr) zv[jr] = bv[n] + (float)acc[n][jr] * f[n];
                    __builtin_nontemporal_store(zv,
                        (f32x4*)(zsl + (size_t)t * 32768 + ((wq * 4 + n) * 64 + l) * 16));
                }

                __syncthreads();            // everyone done reading bufw's old data
                if (pf) *(i32x4*)(bufw + tid * 16) = p0;
                __syncthreads();            // staged slab visible
            }

            __syncthreads();
            if (tid == 0)
                __hip_atomic_store(&F[512 + g * 32 + c], 1, __ATOMIC_RELEASE, __HIP_MEMORY_SCOPE_AGENT);
        }
    }
}

// ---------------------------------------------------------------------------
// Batch-axis softmax stats per hidden column.
// ---------------------------------------------------------------------------
__global__ void colstats_kernel(const float* __restrict__ encoded,
                                float* __restrict__ colmax,
                                float* __restrict__ rsinv)
{
    const int h = blockIdx.x;
    const int lane = threadIdx.x;  // 64
    float v[4];
#pragma unroll
    for (int r = 0; r < 4; ++r) v[r] = encoded[(size_t)(lane + 64 * r) * NH + h];
    float mx = fmaxf(fmaxf(v[0], v[1]), fmaxf(v[2], v[3]));
#pragma unroll
    for (int s = 1; s < 64; s <<= 1) mx = fmaxf(mx, __shfl_xor(mx, s));
    float sum = 0.f;
#pragma unroll
    for (int r = 0; r < 4; ++r) sum += __expf(v[r] - mx);
#pragma unroll
    for (int s = 1; s < 64; s <<= 1) sum += __shfl_xor(sum, s);
    if (lane == 0) { colmax[h] = mx; rsinv[h] = 1.0f / sum; }
}

// ---------------------------------------------------------------------------
// Decoder: one batch element per thread; 4-dim recurrence in registers.
// ---------------------------------------------------------------------------
__global__ void decoder_kernel(
    const float* __restrict__ encoded,
    const float* __restrict__ colmax, const float* __restrict__ rsinv,
    const float* __restrict__ dWih0, const float* __restrict__ dWhh0,
    const float* __restrict__ dbih0, const float* __restrict__ dbhh0,
    const float* __restrict__ dWih1, const float* __restrict__ dWhh1,
    const float* __restrict__ dbih1, const float* __restrict__ dbhh1,
    float* __restrict__ out)
{
    const int b = blockIdx.x * 64 + threadIdx.x;

    float W0[16], Wi[16], W1[16];
#pragma unroll
    for (int e = 0; e < 16; ++e) { W0[e] = dWhh0[e]; Wi[e] = dWih1[e]; W1[e] = dWhh1[e]; }

    float c1[4], c2[4];
#pragma unroll
    for (int j = 0; j < 4; ++j) { c1[j] = dbih0[j] + dbhh0[j]; c2[j] = dbih1[j] + dbhh1[j]; }

    const float* er = encoded + (size_t)b * NH;
#pragma unroll 1
    for (int h = 0; h < NH; h += 4) {
        const float4 ev = *(const float4*)(er + h);
        const float4 cm = *(const float4*)(colmax + h);
        const float4 rs = *(const float4*)(rsinv + h);
        float p0 = __expf(ev.x - cm.x) * rs.x;
        float p1 = __expf(ev.y - cm.y) * rs.y;
        float p2 = __expf(ev.z - cm.z) * rs.z;
        float p3 = __expf(ev.w - cm.w) * rs.w;
#pragma unroll
        for (int j = 0; j < 4; ++j) {
            const float4 w = *(const float4*)(dWih0 + (size_t)j * NH + h);
            c1[j] += p0 * w.x + p1 * w.y + p2 * w.z + p3 * w.w;
        }
    }

    float h1[4] = {0.f, 0.f, 0.f, 0.f};
    float h2[4] = {0.f, 0.f, 0.f, 0.f};
    float* op = out + (size_t)b * NS * NV;

#pragma unroll 1
    for (int t = 0; t < NS; ++t) {
        float n1[4];
#pragma unroll
        for (int j = 0; j < 4; ++j)
            n1[j] = fast_tanh(c1[j] + W0[j*4+0]*h1[0] + W0[j*4+1]*h1[1]
                                    + W0[j*4+2]*h1[2] + W0[j*4+3]*h1[3]);
        float n2[4];
#pragma unroll
        for (int j = 0; j < 4; ++j)
            n2[j] = fast_tanh(c2[j] + Wi[j*4+0]*n1[0] + Wi[j*4+1]*n1[1]
                                    + Wi[j*4+2]*n1[2] + Wi[j*4+3]*n1[3]
                                    + W1[j*4+0]*h2[0] + W1[j*4+1]*h2[1]
                                    + W1[j*4+2]*h2[2] + W1[j*4+3]*h2[3]);
#pragma unroll
        for (int j = 0; j < 4; ++j) { h1[j] = n1[j]; h2[j] = n2[j]; }
        *(float4*)(op + (size_t)t * NV) = make_float4(n2[0], n2[1], n2[2], n2[3]);
    }
}

extern "C" void kernel_launch(void* const* d_in, const int* in_sizes, int n_in,
                              void* d_out, int out_size, void* d_ws, size_t ws_size,
                              hipStream_t stream)
{
    const float* x     = (const float*)d_in[0];
    const float* eWih0 = (const float*)d_in[1];
    const float* eWhh0 = (const float*)d_in[2];
    const float* ebih0 = (const float*)d_in[3];
    const float* ebhh0 = (const float*)d_in[4];
    const float* eWih1 = (const float*)d_in[5];
    const float* eWhh1 = (const float*)d_in[6];
    const float* ebih1 = (const float*)d_in[7];
    const float* ebhh1 = (const float*)d_in[8];
    const float* dWih0 = (const float*)d_in[9];
    const float* dWhh0 = (const float*)d_in[10];
    const float* dbih0 = (const float*)d_in[11];
    const float* dbhh0 = (const float*)d_in[12];
    const float* dWih1 = (const float*)d_in[13];
    const float* dWhh1 = (const float*)d_in[14];
    const float* dbih1 = (const float*)d_in[15];
    const float* dbhh1 = (const float*)d_in[16];

    char*  ws     = (char*)d_ws;
    float* enc    = (float*)(ws + ENC_OFF);
    float* colmax = (float*)(ws + CM_OFF);
    float* rsinv  = (float*)(ws + RS_OFF);

    hipFuncSetAttribute((const void*)persist_kernel,
                        hipFuncAttributeMaxDynamicSharedMemorySize, 147456);

    // zero flags
    hipMemsetAsync(d_ws, 0, 4096, stream);

    // one-shot weight quantization (i8 B-frags + per-col scales)
    prep_kernel<<<96, 256, 0, stream>>>(eWhh0, eWhh1, eWih1, ws);

    // persistent pipelined encoder (i8 weights fully CU-resident)
    persist_kernel<<<48, 512, 147456, stream>>>(x, eWih0, ebih0, ebhh0,
                                                ebih1, ebhh1, ws);

    colstats_kernel<<<NH, 64, 0, stream>>>(enc, colmax, rsinv);
    decoder_kernel<<<4, 64, 0, stream>>>(enc, colmax, rsinv,
                                         dWih0, dWhh0, dbih0, dbhh0,
                                         dWih1, dWhh1, dbih1, dbhh1,
                                         (float*)d_out);
}

// Round 19
// 1439.195 us; speedup vs baseline: 1.2676x; 1.1288x over previous
//
#include <hip/hip_runtime.h>
#include <hip/hip_bf16.h>

#define NB 256   // batch
#define NS 512   // seq len
#define NV 4     // vocab
#define NH 512   // encoder hidden
#define CH 16    // steps per chunk
#define NCH 32   // chunks

typedef __bf16 bf16x8 __attribute__((ext_vector_type(8)));
typedef __bf16 bf16x4 __attribute__((ext_vector_type(4)));
typedef float  f32x4  __attribute__((ext_vector_type(4)));
typedef int    i32x4  __attribute__((ext_vector_type(4)));

// ---- workspace byte offsets ----
// flags 8KB | h1ring(i8) 4MB | zring(bf16) 8MB | enc 512KB | cm/rs | frags_i8 3x256KB | scales 3x2KB
#define H1RING_OFF  8192
#define ZRING_OFF   (H1RING_OFF + (4u << 20))
#define ENC_OFF     (ZRING_OFF + (8u << 20))
#define CM_OFF      (ENC_OFF + NB*NH*4)
#define RS_OFF      (CM_OFF + 2048)
#define FRAG_OFF    (RS_OFF + 2048)
#define SCALE_OFF   (FRAG_OFF + 3*262144)

// tanh(x) = 1 - 2/(e^{2x}+1).  Clamp-free, ~5 VALU ops.
__device__ __forceinline__ float fast_tanh(float x) {
    const float e = __expf(2.0f * x);
    return 1.0f - 2.0f * __frcp_rn(e + 1.0f);
}

__device__ __forceinline__ int aload(int* p) {
    return __hip_atomic_load(p, __ATOMIC_ACQUIRE, __HIP_MEMORY_SCOPE_AGENT);
}

// ---------------------------------------------------------------------------
// One-shot: quantize weight matrices to int8 MFMA B-fragments (16x16x64 i8)
// with per-column scales.  frag layout: ((ks64*32 + gt)*64 + l)*16 bytes.
// ---------------------------------------------------------------------------
__global__ void prep_kernel(const float* __restrict__ W0, const float* __restrict__ W1,
                            const float* __restrict__ WG, char* __restrict__ ws)
{
    const int mt = blockIdx.x >> 5;     // 0=Whh0(A), 1=Whh1(B), 2=Wih1(G)
    const int gt = blockIdx.x & 31;
    const float* src = (mt == 0) ? W0 : (mt == 1) ? W1 : WG;
    char*  dst = ws + FRAG_OFF + (size_t)mt * 262144;
    float* fsc = (float*)(ws + SCALE_OFF) + mt * 512;
    const int tid = threadIdx.x;
    const int cg = tid >> 4, ti = tid & 15;

    __shared__ float cmax[16][17];
    __shared__ float inv[16];

    {
        const int col = gt * 16 + cg;
        float m = 0.f;
        for (int e = ti; e < NH; e += 16) m = fmaxf(m, fabsf(src[(size_t)col * NH + e]));
        cmax[cg][ti] = m;
    }
    __syncthreads();
    if (ti == 0) {
        float mm = 0.f;
#pragma unroll
        for (int j = 0; j < 16; ++j) mm = fmaxf(mm, cmax[cg][j]);
        inv[cg] = (mm > 0.f) ? 127.0f / mm : 0.f;
        fsc[gt * 16 + cg] = mm / (127.0f * 127.0f);
    }
    __syncthreads();

    for (int e = tid; e < 512; e += 256) {
        const int ks = e >> 6, l = e & 63;
        const int c16 = l & 15;
        const float iv = inv[c16];
        const float* p = src + (size_t)(gt * 16 + c16) * NH + ks * 64 + ((l >> 4) << 4);
        int vi[4];
#pragma unroll
        for (int w = 0; w < 4; ++w) {
            int b0 = __float2int_rn(p[w*4+0] * iv) & 255;
            int b1 = __float2int_rn(p[w*4+1] * iv) & 255;
            int b2 = __float2int_rn(p[w*4+2] * iv) & 255;
            int b3 = __float2int_rn(p[w*4+3] * iv) & 255;
            vi[w] = b0 | (b1 << 8) | (b2 << 16) | (b3 << 24);
        }
        *(i32x4*)(dst + ((size_t)(ks * 32 + gt) * 64 + l) * 16) = (i32x4){vi[0], vi[1], vi[2], vi[3]};
    }
}

// ---------------------------------------------------------------------------
// Persistent pipeline: 48 WGs x 512 threads, 1 block/CU.
// i8 weights fully CU-resident (ks64 0-3 VGPR, 4-7 LDS); h state i8 dbuf.
// r19: z ring carried as bf16 (halves G store / B load traffic).
// role A (blk 0-15): h1 chain. role B (16-31): h2 chain. role G (32-47): z.
// ---------------------------------------------------------------------------
extern "C" __global__ __launch_bounds__(512, 1)
void persist_kernel(const float* __restrict__ x,
                    const float* __restrict__ eWih0,
                    const float* __restrict__ ebih0, const float* __restrict__ ebhh0,
                    const float* __restrict__ ebih1, const float* __restrict__ ebhh1,
                    char* __restrict__ ws)
{
    extern __shared__ char lds[];
    int*   F      = (int*)ws;
    char*  h1ring = ws + H1RING_OFF;
    char*  zring  = ws + ZRING_OFF;
    float* enc    = (float*)(ws + ENC_OFF);

    const int blk  = blockIdx.x;
    const int role = blk >> 4;     // 0=A, 1=B, 2=G
    const int g    = blk & 15;
    const int tid  = threadIdx.x;
    const int wq   = tid >> 6;     // wave 0..7
    const int l    = tid & 63;
    const int lm   = l & 15;
    const int q    = l >> 4;

    const int mt = (role == 0) ? 0 : (role == 1) ? 1 : 2;
    const char*  frag = ws + FRAG_OFF + (size_t)mt * 262144;
    const float* fsc  = (const float*)(ws + SCALE_OFF) + mt * 512;

    char* HS = lds;            // [0,16384) h_i8 double buffer (2 x 8KB)
    char* WL = lds + 16384;    // [16384,147456) ks64 4..7 i8 slabs (4 x 32KB)

    // ---- weights: ks64 0-3 resident in VGPR, ks64 4-7 into LDS ----
    i32x4 WR[4][4];
#pragma unroll
    for (int ks = 0; ks < 4; ++ks)
#pragma unroll
        for (int n = 0; n < 4; ++n)
            WR[ks][n] = *(const i32x4*)(frag + ((size_t)(ks * 32 + wq * 4 + n) * 64 + l) * 16);
#pragma unroll
    for (int ks = 4; ks < 8; ++ks)
#pragma unroll
        for (int n = 0; n < 4; ++n) {
            const i32x4 v = *(const i32x4*)(frag + ((size_t)(ks * 32 + wq * 4 + n) * 64 + l) * 16);
            *(i32x4*)(WL + (((ks - 4) * 32 + wq * 4 + n) * 64 + l) * 16) = v;
        }
    float f[4];
#pragma unroll
    for (int n = 0; n < 4; ++n) f[n] = fsc[wq * 64 + n * 16 + lm];

    if (role <= 1) {
        // ================= chain roles (A: layer-0, B: layer-1) =================
        const bool isA = (role == 0);

        // zero h_i8 state (both buffers)
        {
            for (int o = tid; o < 512; o += 512) *(f32x4*)(HS + o * 32) = (f32x4){0.f,0.f,0.f,0.f};
            *(f32x4*)(HS + tid * 32 + 16) = (f32x4){0.f,0.f,0.f,0.f};
        }

        bf16x8 EB[4];
        float  bias[4];
#pragma unroll
        for (int n = 0; n < 4; ++n) {
            const int col = wq * 64 + n * 16 + lm;
#pragma unroll
            for (int j = 0; j < 8; ++j) EB[n][j] = (__bf16)0.f;
            if (isA) {
                if (q == 0) {
                    const float4 w0 = *(const float4*)(eWih0 + (size_t)col * NV);
                    EB[n][0] = (__bf16)w0.x; EB[n][1] = (__bf16)w0.y;
                    EB[n][2] = (__bf16)w0.z; EB[n][3] = (__bf16)w0.w;
                }
                bias[n] = ebih0[col] + ebhh0[col];
            } else {
                bias[n] = 0.f;  // z already contains layer-1 biases
            }
        }
        __syncthreads();

        const float* xrow = x + (size_t)(g * 16 + lm) * NS * NV;   // A's x row base

#pragma unroll 1
        for (int c = 0; c < NCH; ++c) {
            // ---- chunk-entry sync ----
            if (isA) {
                if (c >= 2) {   // backpressure: G consumed h1 chunk c-2 (same parity)
                    if (tid == 0)
                        while (aload(&F[512 + g * 32 + (c - 2)]) < 1)
                            __builtin_amdgcn_s_sleep(2);
                    __syncthreads();
                }
            } else {
                if (tid == 0)
                    while (aload(&F[512 + g * 32 + c]) < 1)
                        __builtin_amdgcn_s_sleep(2);
                __syncthreads();
                __builtin_amdgcn_fence(__ATOMIC_ACQUIRE, "agent");
            }

            char* rsl = h1ring + (size_t)((g * 2 + (c & 1)) * CH) * 8192;   // A writes (i8)
            char* zsl = zring  + (size_t)((g * 2 + (c & 1)) * CH) * 16384;  // B reads (bf16)

            bf16x4 zn[4];
            float4 xv;
            if (isA) {
                xv = *(const float4*)(xrow + (size_t)(c * CH) * NV);        // prefetch t=0
            } else {
#pragma unroll
                for (int n = 0; n < 4; ++n)
                    zn[n] = __builtin_nontemporal_load(
                        (const bf16x4*)(zsl + ((wq * 4 + n) * 64 + l) * 8));
            }

#pragma unroll 1
            for (int t = 0; t < CH; ++t) {
                const int i  = c * CH + t;
                const int rb = t & 1;
                const char* hsr = HS + rb * 8192;
                char*       hsw = HS + (rb ^ 1) * 8192;

                i32x4 acc[4];
#pragma unroll
                for (int n = 0; n < 4; ++n) acc[n] = (i32x4){0, 0, 0, 0};
                f32x4 xacc[4];
                bf16x8 xa;
                if (isA) {
#pragma unroll
                    for (int n = 0; n < 4; ++n)
                        xacc[n] = (f32x4){bias[n], bias[n], bias[n], bias[n]};
#pragma unroll
                    for (int j = 0; j < 8; ++j) xa[j] = (__bf16)0.f;
                    if (q == 0) {
                        xa[0] = (__bf16)xv.x; xa[1] = (__bf16)xv.y;
                        xa[2] = (__bf16)xv.z; xa[3] = (__bf16)xv.w;
                    }
                    if (t + 1 < CH)                                       // prefetch next x
                        xv = *(const float4*)(xrow + (size_t)(i + 1) * NV);
#pragma unroll
                    for (int n = 0; n < 4; ++n)
                        xacc[n] = __builtin_amdgcn_mfma_f32_16x16x32_bf16(xa, EB[n], xacc[n], 0, 0, 0);
                } else {
#pragma unroll
                    for (int n = 0; n < 4; ++n) {
#pragma unroll
                        for (int jr = 0; jr < 4; ++jr) xacc[n][jr] = (float)zn[n][jr];
                    }
                    if (t + 1 < CH) {
#pragma unroll
                        for (int n = 0; n < 4; ++n)
                            zn[n] = __builtin_nontemporal_load(
                                (const bf16x4*)(zsl + (size_t)(t + 1) * 16384 +
                                                ((wq * 4 + n) * 64 + l) * 8));
                    }
                }

                // ---- K-steps: 4 resident + 4 LDS, K=64 each ----
#pragma unroll
                for (int ks = 0; ks < 4; ++ks) {
                    const i32x4 af = *(const i32x4*)(hsr + ks * 1024 + l * 16);
#pragma unroll
                    for (int n = 0; n < 4; ++n)
                        acc[n] = __builtin_amdgcn_mfma_i32_16x16x64_i8(af, WR[ks][n], acc[n], 0, 0, 0);
                }
#pragma unroll
                for (int ks = 4; ks < 8; ++ks) {
                    const i32x4 af = *(const i32x4*)(hsr + ks * 1024 + l * 16);
#pragma unroll
                    for (int n = 0; n < 4; ++n) {
                        const i32x4 bfr = *(const i32x4*)(WL + (((ks - 4) * 32 + wq * 4 + n) * 64 + l) * 16);
                        acc[n] = __builtin_amdgcn_mfma_i32_16x16x64_i8(af, bfr, acc[n], 0, 0, 0);
                    }
                }

                // ---- dequant + epilogue ----
                if (!isA && i == NS - 1) {
                    // encoded = PRE-tanh (arctanh(tanh(s)) == s)
#pragma unroll
                    for (int n = 0; n < 4; ++n) {
                        const int col = wq * 64 + n * 16 + lm;
#pragma unroll
                        for (int jr = 0; jr < 4; ++jr)
                            enc[(size_t)(g * 16 + q * 4 + jr) * NH + col] =
                                xacc[n][jr] + (float)acc[n][jr] * f[n];
                    }
                } else {
#pragma unroll
                    for (int n = 0; n < 4; ++n) {
#pragma unroll
                        for (int jr = 0; jr < 4; ++jr) {
                            const float s  = xacc[n][jr] + (float)acc[n][jr] * f[n];
                            const float th = fast_tanh(s);
                            const int slot = (q * 4 + jr) | (n << 4);
                            *(char*)(hsw + wq * 1024 + slot * 16 + lm) =
                                (char)__float2int_rn(th * 127.0f);
                        }
                    }
                }
                __syncthreads();  // hsw complete for all waves

                if (isA) {
                    // copy new h1_i8 (8 KB) -> h1ring, NT
                    const i32x4 v = *(const i32x4*)(hsw + tid * 16);
                    __builtin_nontemporal_store(v, (i32x4*)(rsl + (size_t)t * 8192 + tid * 16));
                }
            }

            // ---- chunk-exit publish ----
            __syncthreads();
            if (tid == 0) {
                if (isA)
                    __hip_atomic_store(&F[g * 16], c + 1, __ATOMIC_RELEASE, __HIP_MEMORY_SCOPE_AGENT);
                else
                    __hip_atomic_store(&F[256 + g * 16], c + 1, __ATOMIC_RELEASE, __HIP_MEMORY_SCOPE_AGENT);
            }
        }
    } else {
        // ================= G role: z[c] = h1[c] @ Wih1^T + bias (bf16 out) ======
        float bv[4];
#pragma unroll
        for (int n = 0; n < 4; ++n) {
            const int col = wq * 64 + n * 16 + lm;
            bv[n] = ebih1[col] + ebhh1[col];
        }
        __syncthreads();

#pragma unroll 1
        for (int c = 0; c < NCH; ++c) {
            if (tid == 0) {
                while (aload(&F[g * 16]) < c + 1) __builtin_amdgcn_s_sleep(2);
                if (c >= 2)
                    while (aload(&F[256 + g * 16]) < c - 1) __builtin_amdgcn_s_sleep(2);
            }
            __syncthreads();
            __builtin_amdgcn_fence(__ATOMIC_ACQUIRE, "agent");

            const char* rsl = h1ring + (size_t)((g * 2 + (c & 1)) * CH) * 8192;
            char*       zsl = zring  + (size_t)((g * 2 + (c & 1)) * CH) * 16384;

            // stage t=0 (16 B/thread, 8 KB slab)
            *(i32x4*)(HS + tid * 16) =
                __builtin_nontemporal_load((const i32x4*)(rsl + tid * 16));
            __syncthreads();

#pragma unroll 1
            for (int t = 0; t < CH; ++t) {
                const char* bufr = HS + (t & 1) * 8192;
                char*       bufw = HS + ((t + 1) & 1) * 8192;
                i32x4 p0;
                const bool pf = (t + 1 < CH);
                if (pf) p0 = __builtin_nontemporal_load(
                            (const i32x4*)(rsl + (size_t)(t + 1) * 8192 + tid * 16));

                i32x4 acc[4];
#pragma unroll
                for (int n = 0; n < 4; ++n) acc[n] = (i32x4){0, 0, 0, 0};
#pragma unroll
                for (int ks = 0; ks < 4; ++ks) {
                    const i32x4 af = *(const i32x4*)(bufr + ks * 1024 + l * 16);
#pragma unroll
                    for (int n = 0; n < 4; ++n)
                        acc[n] = __builtin_amdgcn_mfma_i32_16x16x64_i8(af, WR[ks][n], acc[n], 0, 0, 0);
                }
#pragma unroll
                for (int ks = 4; ks < 8; ++ks) {
                    const i32x4 af = *(const i32x4*)(bufr + ks * 1024 + l * 16);
#pragma unroll
                    for (int n = 0; n < 4; ++n) {
                        const i32x4 bfr = *(const i32x4*)(WL + (((ks - 4) * 32 + wq * 4 + n) * 64 + l) * 16);
                        acc[n] = __builtin_amdgcn_mfma_i32_16x16x64_i8(af, bfr, acc[n], 0, 0, 0);
                    }
                }
#pragma unroll
                for (int n = 0; n < 4; ++n) {
                    bf16x4 zb;
#pragma unroll
                    for (int jr = 0; jr < 4; ++jr)
                        zb[jr] = (__bf16)(bv[n] + (float)acc[n][jr] * f[n]);
                    __builtin_nontemporal_store(zb,
                        (bf16x4*)(zsl + (size_t)t * 16384 + ((wq * 4 + n) * 64 + l) * 8));
                }

                __syncthreads();            // everyone done reading bufw's old data
                if (pf) *(i32x4*)(bufw + tid * 16) = p0;
                __syncthreads();            // staged slab visible
            }

            __syncthreads();
            if (tid == 0)
                __hip_atomic_store(&F[512 + g * 32 + c], 1, __ATOMIC_RELEASE, __HIP_MEMORY_SCOPE_AGENT);
        }
    }
}

// ---------------------------------------------------------------------------
// Batch-axis softmax stats per hidden column.
// ---------------------------------------------------------------------------
__global__ void colstats_kernel(const float* __restrict__ encoded,
                                float* __restrict__ colmax,
                                float* __restrict__ rsinv)
{
    const int h = blockIdx.x;
    const int lane = threadIdx.x;  // 64
    float v[4];
#pragma unroll
    for (int r = 0; r < 4; ++r) v[r] = encoded[(size_t)(lane + 64 * r) * NH + h];
    float mx = fmaxf(fmaxf(v[0], v[1]), fmaxf(v[2], v[3]));
#pragma unroll
    for (int s = 1; s < 64; s <<= 1) mx = fmaxf(mx, __shfl_xor(mx, s));
    float sum = 0.f;
#pragma unroll
    for (int r = 0; r < 4; ++r) sum += __expf(v[r] - mx);
#pragma unroll
    for (int s = 1; s < 64; s <<= 1) sum += __shfl_xor(sum, s);
    if (lane == 0) { colmax[h] = mx; rsinv[h] = 1.0f / sum; }
}

// ---------------------------------------------------------------------------
// Decoder: 4 blocks x 256 threads.  a1 phase: 4-way h-split per batch
// (quarter = tid>>6) with LDS reduce -> 4x the waves hiding L2 latency.
// Recurrence: quarter-0 threads only (one batch element per thread).
// ---------------------------------------------------------------------------
__global__ void decoder_kernel(
    const float* __restrict__ encoded,
    const float* __restrict__ colmax, const float* __restrict__ rsinv,
    const float* __restrict__ dWih0, const float* __restrict__ dWhh0,
    const float* __restrict__ dbih0, const float* __restrict__ dbhh0,
    const float* __restrict__ dWih1, const float* __restrict__ dWhh1,
    const float* __restrict__ dbih1, const float* __restrict__ dbhh1,
    float* __restrict__ out)
{
    const int tid = threadIdx.x;          // 256
    const int bl  = tid & 63;             // local batch
    const int qh  = tid >> 6;             // h quarter
    const int b   = blockIdx.x * 64 + bl;

    __shared__ float part[4][64][4];

    float c1p[4] = {0.f, 0.f, 0.f, 0.f};
    const float* er = encoded + (size_t)b * NH;
#pragma unroll 1
    for (int h = qh * 128; h < qh * 128 + 128; h += 4) {
        const float4 ev = *(const float4*)(er + h);
        const float4 cm = *(const float4*)(colmax + h);
        const float4 rs = *(const float4*)(rsinv + h);
        float p0 = __expf(ev.x - cm.x) * rs.x;
        float p1 = __expf(ev.y - cm.y) * rs.y;
        float p2 = __expf(ev.z - cm.z) * rs.z;
        float p3 = __expf(ev.w - cm.w) * rs.w;
#pragma unroll
        for (int j = 0; j < 4; ++j) {
            const float4 w = *(const float4*)(dWih0 + (size_t)j * NH + h);
            c1p[j] += p0 * w.x + p1 * w.y + p2 * w.z + p3 * w.w;
        }
    }
#pragma unroll
    for (int j = 0; j < 4; ++j) part[qh][bl][j] = c1p[j];
    __syncthreads();
    if (qh != 0) return;

    float W0[16], Wi[16], W1[16];
#pragma unroll
    for (int e = 0; e < 16; ++e) { W0[e] = dWhh0[e]; Wi[e] = dWih1[e]; W1[e] = dWhh1[e]; }

    float c1[4], c2[4];
#pragma unroll
    for (int j = 0; j < 4; ++j) {
        c1[j] = dbih0[j] + dbhh0[j]
              + part[0][bl][j] + part[1][bl][j] + part[2][bl][j] + part[3][bl][j];
        c2[j] = dbih1[j] + dbhh1[j];
    }

    float h1[4] = {0.f, 0.f, 0.f, 0.f};
    float h2[4] = {0.f, 0.f, 0.f, 0.f};
    float* op = out + (size_t)b * NS * NV;

#pragma unroll 1
    for (int t = 0; t < NS; ++t) {
        float n1[4];
#pragma unroll
        for (int j = 0; j < 4; ++j)
            n1[j] = fast_tanh(c1[j] + W0[j*4+0]*h1[0] + W0[j*4+1]*h1[1]
                                    + W0[j*4+2]*h1[2] + W0[j*4+3]*h1[3]);
        float n2[4];
#pragma unroll
        for (int j = 0; j < 4; ++j)
            n2[j] = fast_tanh(c2[j] + Wi[j*4+0]*n1[0] + Wi[j*4+1]*n1[1]
                                    + Wi[j*4+2]*n1[2] + Wi[j*4+3]*n1[3]
                                    + W1[j*4+0]*h2[0] + W1[j*4+1]*h2[1]
                                    + W1[j*4+2]*h2[2] + W1[j*4+3]*h2[3]);
#pragma unroll
        for (int j = 0; j < 4; ++j) { h1[j] = n1[j]; h2[j] = n2[j]; }
        *(float4*)(op + (size_t)t * NV) = make_float4(n2[0], n2[1], n2[2], n2[3]);
    }
}

extern "C" void kernel_launch(void* const* d_in, const int* in_sizes, int n_in,
                              void* d_out, int out_size, void* d_ws, size_t ws_size,
                              hipStream_t stream)
{
    const float* x     = (const float*)d_in[0];
    const float* eWih0 = (const float*)d_in[1];
    const float* eWhh0 = (const float*)d_in[2];
    const float* ebih0 = (const float*)d_in[3];
    const float* ebhh0 = (const float*)d_in[4];
    const float* eWih1 = (const float*)d_in[5];
    const float* eWhh1 = (const float*)d_in[6];
    const float* ebih1 = (const float*)d_in[7];
    const float* ebhh1 = (const float*)d_in[8];
    const float* dWih0 = (const float*)d_in[9];
    const float* dWhh0 = (const float*)d_in[10];
    const float* dbih0 = (const float*)d_in[11];
    const float* dbhh0 = (const float*)d_in[12];
    const float* dWih1 = (const float*)d_in[13];
    const float* dWhh1 = (const float*)d_in[14];
    const float* dbih1 = (const float*)d_in[15];
    const float* dbhh1 = (const float*)d_in[16];

    char*  ws     = (char*)d_ws;
    float* enc    = (float*)(ws + ENC_OFF);
    float* colmax = (float*)(ws + CM_OFF);
    float* rsinv  = (float*)(ws + RS_OFF);

    hipFuncSetAttribute((const void*)persist_kernel,
                        hipFuncAttributeMaxDynamicSharedMemorySize, 147456);

    // zero flags
    hipMemsetAsync(d_ws, 0, 4096, stream);

    // one-shot weight quantization (i8 B-frags + per-col scales)
    prep_kernel<<<96, 256, 0, stream>>>(eWhh0, eWhh1, eWih1, ws);

    // persistent pipelined encoder (i8 weights fully CU-resident)
    persist_kernel<<<48, 512, 147456, stream>>>(x, eWih0, ebih0, ebhh0,
                                                ebih1, ebhh1, ws);

    colstats_kernel<<<NH, 64, 0, stream>>>(enc, colmax, rsinv);
    decoder_kernel<<<4, 256, 0, stream>>>(enc, colmax, rsinv,
                                          dWih0, dWhh0, dbih0, dbhh0,
                                          dWih1, dWhh1, dbih1, dbhh1,
                                          (float*)d_out);
}

// Round 20
// 1430.408 us; speedup vs baseline: 1.2754x; 1.0061x over previous
//
#include <hip/hip_runtime.h>
#include <hip/hip_bf16.h>

#define NB 256   // batch
#define NS 512   // seq len
#define NV 4     // vocab
#define NH 512   // encoder hidden
#define CH 16    // steps per chunk
#define NCH 32   // chunks

typedef __bf16 bf16x8 __attribute__((ext_vector_type(8)));
typedef __bf16 bf16x4 __attribute__((ext_vector_type(4)));
typedef float  f32x4  __attribute__((ext_vector_type(4)));
typedef int    i32x4  __attribute__((ext_vector_type(4)));

// ---- workspace byte offsets ----
// flags 8KB | h1ring(i8) 4MB | zring(bf16) 8MB | enc 512KB | cm/rs | frags_i8 3x256KB | scales 3x2KB
#define H1RING_OFF  8192
#define ZRING_OFF   (H1RING_OFF + (4u << 20))
#define ENC_OFF     (ZRING_OFF + (8u << 20))
#define CM_OFF      (ENC_OFF + NB*NH*4)
#define RS_OFF      (CM_OFF + 2048)
#define FRAG_OFF    (RS_OFF + 2048)
#define SCALE_OFF   (FRAG_OFF + 3*262144)

// tanh(x) = 1 - 2/(e^{2x}+1).  Clamp-free, ~5 VALU ops.
__device__ __forceinline__ float fast_tanh(float x) {
    const float e = __expf(2.0f * x);
    return 1.0f - 2.0f * __frcp_rn(e + 1.0f);
}

__device__ __forceinline__ int aload(int* p) {
    return __hip_atomic_load(p, __ATOMIC_ACQUIRE, __HIP_MEMORY_SCOPE_AGENT);
}

// LDS-only barrier: wait on this wave's LDS ops, then s_barrier.  Does NOT
// drain vmcnt -> per-step NT ring stores/loads stay in flight (they are only
// consumed after the chunk-exit full __syncthreads + release-store).
// sched_barrier(0) pins following ops behind the waitcnt (rule #18).
__device__ __forceinline__ void lds_barrier() {
    asm volatile("s_waitcnt lgkmcnt(0)" ::: "memory");
    __builtin_amdgcn_sched_barrier(0);
    __builtin_amdgcn_s_barrier();
}

// ---------------------------------------------------------------------------
// One-shot: quantize weight matrices to int8 MFMA B-fragments (16x16x64 i8)
// with per-column scales.  frag layout: ((ks64*32 + gt)*64 + l)*16 bytes.
// ---------------------------------------------------------------------------
__global__ void prep_kernel(const float* __restrict__ W0, const float* __restrict__ W1,
                            const float* __restrict__ WG, char* __restrict__ ws)
{
    const int mt = blockIdx.x >> 5;     // 0=Whh0(A), 1=Whh1(B), 2=Wih1(G)
    const int gt = blockIdx.x & 31;
    const float* src = (mt == 0) ? W0 : (mt == 1) ? W1 : WG;
    char*  dst = ws + FRAG_OFF + (size_t)mt * 262144;
    float* fsc = (float*)(ws + SCALE_OFF) + mt * 512;
    const int tid = threadIdx.x;
    const int cg = tid >> 4, ti = tid & 15;

    __shared__ float cmax[16][17];
    __shared__ float inv[16];

    {
        const int col = gt * 16 + cg;
        float m = 0.f;
        for (int e = ti; e < NH; e += 16) m = fmaxf(m, fabsf(src[(size_t)col * NH + e]));
        cmax[cg][ti] = m;
    }
    __syncthreads();
    if (ti == 0) {
        float mm = 0.f;
#pragma unroll
        for (int j = 0; j < 16; ++j) mm = fmaxf(mm, cmax[cg][j]);
        inv[cg] = (mm > 0.f) ? 127.0f / mm : 0.f;
        fsc[gt * 16 + cg] = mm / (127.0f * 127.0f);
    }
    __syncthreads();

    for (int e = tid; e < 512; e += 256) {
        const int ks = e >> 6, l = e & 63;
        const int c16 = l & 15;
        const float iv = inv[c16];
        const float* p = src + (size_t)(gt * 16 + c16) * NH + ks * 64 + ((l >> 4) << 4);
        int vi[4];
#pragma unroll
        for (int w = 0; w < 4; ++w) {
            int b0 = __float2int_rn(p[w*4+0] * iv) & 255;
            int b1 = __float2int_rn(p[w*4+1] * iv) & 255;
            int b2 = __float2int_rn(p[w*4+2] * iv) & 255;
            int b3 = __float2int_rn(p[w*4+3] * iv) & 255;
            vi[w] = b0 | (b1 << 8) | (b2 << 16) | (b3 << 24);
        }
        *(i32x4*)(dst + ((size_t)(ks * 32 + gt) * 64 + l) * 16) = (i32x4){vi[0], vi[1], vi[2], vi[3]};
    }
}

// ---------------------------------------------------------------------------
// Persistent pipeline: 48 WGs x 512 threads, 1 block/CU.
// i8 weights fully CU-resident (ks64 0-3 VGPR, 4-7 LDS); h state i8 dbuf;
// z ring bf16.  r20: per-step barriers are LDS-only (no vmcnt drain) -- the
// NT ring stores ack in the background and are fenced once per chunk.
// role A (blk 0-15): h1 chain. role B (16-31): h2 chain. role G (32-47): z.
// ---------------------------------------------------------------------------
extern "C" __global__ __launch_bounds__(512, 1)
void persist_kernel(const float* __restrict__ x,
                    const float* __restrict__ eWih0,
                    const float* __restrict__ ebih0, const float* __restrict__ ebhh0,
                    const float* __restrict__ ebih1, const float* __restrict__ ebhh1,
                    char* __restrict__ ws)
{
    extern __shared__ char lds[];
    int*   F      = (int*)ws;
    char*  h1ring = ws + H1RING_OFF;
    char*  zring  = ws + ZRING_OFF;
    float* enc    = (float*)(ws + ENC_OFF);

    const int blk  = blockIdx.x;
    const int role = blk >> 4;     // 0=A, 1=B, 2=G
    const int g    = blk & 15;
    const int tid  = threadIdx.x;
    const int wq   = tid >> 6;     // wave 0..7
    const int l    = tid & 63;
    const int lm   = l & 15;
    const int q    = l >> 4;

    const int mt = (role == 0) ? 0 : (role == 1) ? 1 : 2;
    const char*  frag = ws + FRAG_OFF + (size_t)mt * 262144;
    const float* fsc  = (const float*)(ws + SCALE_OFF) + mt * 512;

    char* HS = lds;            // [0,16384) h_i8 double buffer (2 x 8KB)
    char* WL = lds + 16384;    // [16384,147456) ks64 4..7 i8 slabs (4 x 32KB)

    // ---- weights: ks64 0-3 resident in VGPR, ks64 4-7 into LDS ----
    i32x4 WR[4][4];
#pragma unroll
    for (int ks = 0; ks < 4; ++ks)
#pragma unroll
        for (int n = 0; n < 4; ++n)
            WR[ks][n] = *(const i32x4*)(frag + ((size_t)(ks * 32 + wq * 4 + n) * 64 + l) * 16);
#pragma unroll
    for (int ks = 4; ks < 8; ++ks)
#pragma unroll
        for (int n = 0; n < 4; ++n) {
            const i32x4 v = *(const i32x4*)(frag + ((size_t)(ks * 32 + wq * 4 + n) * 64 + l) * 16);
            *(i32x4*)(WL + (((ks - 4) * 32 + wq * 4 + n) * 64 + l) * 16) = v;
        }
    float f[4];
#pragma unroll
    for (int n = 0; n < 4; ++n) f[n] = fsc[wq * 64 + n * 16 + lm];

    if (role <= 1) {
        // ================= chain roles (A: layer-0, B: layer-1) =================
        const bool isA = (role == 0);

        // zero h_i8 state (both buffers)
        {
            for (int o = tid; o < 512; o += 512) *(f32x4*)(HS + o * 32) = (f32x4){0.f,0.f,0.f,0.f};
            *(f32x4*)(HS + tid * 32 + 16) = (f32x4){0.f,0.f,0.f,0.f};
        }

        bf16x8 EB[4];
        float  bias[4];
#pragma unroll
        for (int n = 0; n < 4; ++n) {
            const int col = wq * 64 + n * 16 + lm;
#pragma unroll
            for (int j = 0; j < 8; ++j) EB[n][j] = (__bf16)0.f;
            if (isA) {
                if (q == 0) {
                    const float4 w0 = *(const float4*)(eWih0 + (size_t)col * NV);
                    EB[n][0] = (__bf16)w0.x; EB[n][1] = (__bf16)w0.y;
                    EB[n][2] = (__bf16)w0.z; EB[n][3] = (__bf16)w0.w;
                }
                bias[n] = ebih0[col] + ebhh0[col];
            } else {
                bias[n] = 0.f;  // z already contains layer-1 biases
            }
        }
        __syncthreads();

        const float* xrow = x + (size_t)(g * 16 + lm) * NS * NV;   // A's x row base

#pragma unroll 1
        for (int c = 0; c < NCH; ++c) {
            // ---- chunk-entry sync ----
            if (isA) {
                if (c >= 2) {   // backpressure: G consumed h1 chunk c-2 (same parity)
                    if (tid == 0)
                        while (aload(&F[512 + g * 32 + (c - 2)]) < 1)
                            __builtin_amdgcn_s_sleep(2);
                    __syncthreads();
                }
            } else {
                if (tid == 0)
                    while (aload(&F[512 + g * 32 + c]) < 1)
                        __builtin_amdgcn_s_sleep(2);
                __syncthreads();
                __builtin_amdgcn_fence(__ATOMIC_ACQUIRE, "agent");
            }

            char* rsl = h1ring + (size_t)((g * 2 + (c & 1)) * CH) * 8192;   // A writes (i8)
            char* zsl = zring  + (size_t)((g * 2 + (c & 1)) * CH) * 16384;  // B reads (bf16)

            bf16x4 zn[4];
            float4 xv;
            if (isA) {
                xv = *(const float4*)(xrow + (size_t)(c * CH) * NV);        // prefetch t=0
            } else {
#pragma unroll
                for (int n = 0; n < 4; ++n)
                    zn[n] = __builtin_nontemporal_load(
                        (const bf16x4*)(zsl + ((wq * 4 + n) * 64 + l) * 8));
            }

#pragma unroll 1
            for (int t = 0; t < CH; ++t) {
                const int i  = c * CH + t;
                const int rb = t & 1;
                const char* hsr = HS + rb * 8192;
                char*       hsw = HS + (rb ^ 1) * 8192;

                i32x4 acc[4];
#pragma unroll
                for (int n = 0; n < 4; ++n) acc[n] = (i32x4){0, 0, 0, 0};
                f32x4 xacc[4];
                bf16x8 xa;
                if (isA) {
#pragma unroll
                    for (int n = 0; n < 4; ++n)
                        xacc[n] = (f32x4){bias[n], bias[n], bias[n], bias[n]};
#pragma unroll
                    for (int j = 0; j < 8; ++j) xa[j] = (__bf16)0.f;
                    if (q == 0) {
                        xa[0] = (__bf16)xv.x; xa[1] = (__bf16)xv.y;
                        xa[2] = (__bf16)xv.z; xa[3] = (__bf16)xv.w;
                    }
                    if (t + 1 < CH)                                       // prefetch next x
                        xv = *(const float4*)(xrow + (size_t)(i + 1) * NV);
#pragma unroll
                    for (int n = 0; n < 4; ++n)
                        xacc[n] = __builtin_amdgcn_mfma_f32_16x16x32_bf16(xa, EB[n], xacc[n], 0, 0, 0);
                } else {
#pragma unroll
                    for (int n = 0; n < 4; ++n) {
#pragma unroll
                        for (int jr = 0; jr < 4; ++jr) xacc[n][jr] = (float)zn[n][jr];
                    }
                    if (t + 1 < CH) {
#pragma unroll
                        for (int n = 0; n < 4; ++n)
                            zn[n] = __builtin_nontemporal_load(
                                (const bf16x4*)(zsl + (size_t)(t + 1) * 16384 +
                                                ((wq * 4 + n) * 64 + l) * 8));
                    }
                }

                // ---- K-steps: 4 resident + 4 LDS, K=64 each ----
#pragma unroll
                for (int ks = 0; ks < 4; ++ks) {
                    const i32x4 af = *(const i32x4*)(hsr + ks * 1024 + l * 16);
#pragma unroll
                    for (int n = 0; n < 4; ++n)
                        acc[n] = __builtin_amdgcn_mfma_i32_16x16x64_i8(af, WR[ks][n], acc[n], 0, 0, 0);
                }
#pragma unroll
                for (int ks = 4; ks < 8; ++ks) {
                    const i32x4 af = *(const i32x4*)(hsr + ks * 1024 + l * 16);
#pragma unroll
                    for (int n = 0; n < 4; ++n) {
                        const i32x4 bfr = *(const i32x4*)(WL + (((ks - 4) * 32 + wq * 4 + n) * 64 + l) * 16);
                        acc[n] = __builtin_amdgcn_mfma_i32_16x16x64_i8(af, bfr, acc[n], 0, 0, 0);
                    }
                }

                // ---- dequant + epilogue ----
                if (!isA && i == NS - 1) {
                    // encoded = PRE-tanh (arctanh(tanh(s)) == s)
#pragma unroll
                    for (int n = 0; n < 4; ++n) {
                        const int col = wq * 64 + n * 16 + lm;
#pragma unroll
                        for (int jr = 0; jr < 4; ++jr)
                            enc[(size_t)(g * 16 + q * 4 + jr) * NH + col] =
                                xacc[n][jr] + (float)acc[n][jr] * f[n];
                    }
                } else {
#pragma unroll
                    for (int n = 0; n < 4; ++n) {
#pragma unroll
                        for (int jr = 0; jr < 4; ++jr) {
                            const float s  = xacc[n][jr] + (float)acc[n][jr] * f[n];
                            const float th = fast_tanh(s);
                            const int slot = (q * 4 + jr) | (n << 4);
                            *(char*)(hsw + wq * 1024 + slot * 16 + lm) =
                                (char)__float2int_rn(th * 127.0f);
                        }
                    }
                }
                lds_barrier();   // hsw visible to all waves; NT stores NOT drained

                if (isA) {
                    // copy new h1_i8 (8 KB) -> h1ring, NT (acked by chunk-exit sync)
                    const i32x4 v = *(const i32x4*)(hsw + tid * 16);
                    __builtin_nontemporal_store(v, (i32x4*)(rsl + (size_t)t * 8192 + tid * 16));
                }
            }

            // ---- chunk-exit publish (full sync: drains vmcnt incl. NT stores) ----
            __syncthreads();
            if (tid == 0) {
                if (isA)
                    __hip_atomic_store(&F[g * 16], c + 1, __ATOMIC_RELEASE, __HIP_MEMORY_SCOPE_AGENT);
                else
                    __hip_atomic_store(&F[256 + g * 16], c + 1, __ATOMIC_RELEASE, __HIP_MEMORY_SCOPE_AGENT);
            }
        }
    } else {
        // ================= G role: z[c] = h1[c] @ Wih1^T + bias (bf16 out) ======
        float bv[4];
#pragma unroll
        for (int n = 0; n < 4; ++n) {
            const int col = wq * 64 + n * 16 + lm;
            bv[n] = ebih1[col] + ebhh1[col];
        }
        __syncthreads();

#pragma unroll 1
        for (int c = 0; c < NCH; ++c) {
            if (tid == 0) {
                while (aload(&F[g * 16]) < c + 1) __builtin_amdgcn_s_sleep(2);
                if (c >= 2)
                    while (aload(&F[256 + g * 16]) < c - 1) __builtin_amdgcn_s_sleep(2);
            }
            __syncthreads();
            __builtin_amdgcn_fence(__ATOMIC_ACQUIRE, "agent");

            const char* rsl = h1ring + (size_t)((g * 2 + (c & 1)) * CH) * 8192;
            char*       zsl = zring  + (size_t)((g * 2 + (c & 1)) * CH) * 16384;

            // stage t=0 (16 B/thread, 8 KB slab)
            *(i32x4*)(HS + tid * 16) =
                __builtin_nontemporal_load((const i32x4*)(rsl + tid * 16));
            lds_barrier();

#pragma unroll 1
            for (int t = 0; t < CH; ++t) {
                const char* bufr = HS + (t & 1) * 8192;
                char*       bufw = HS + ((t + 1) & 1) * 8192;
                i32x4 p0;
                const bool pf = (t + 1 < CH);
                if (pf) p0 = __builtin_nontemporal_load(
                            (const i32x4*)(rsl + (size_t)(t + 1) * 8192 + tid * 16));

                i32x4 acc[4];
#pragma unroll
                for (int n = 0; n < 4; ++n) acc[n] = (i32x4){0, 0, 0, 0};
#pragma unroll
                for (int ks = 0; ks < 4; ++ks) {
                    const i32x4 af = *(const i32x4*)(bufr + ks * 1024 + l * 16);
#pragma unroll
                    for (int n = 0; n < 4; ++n)
                        acc[n] = __builtin_amdgcn_mfma_i32_16x16x64_i8(af, WR[ks][n], acc[n], 0, 0, 0);
                }
#pragma unroll
                for (int ks = 4; ks < 8; ++ks) {
                    const i32x4 af = *(const i32x4*)(bufr + ks * 1024 + l * 16);
#pragma unroll
                    for (int n = 0; n < 4; ++n) {
                        const i32x4 bfr = *(const i32x4*)(WL + (((ks - 4) * 32 + wq * 4 + n) * 64 + l) * 16);
                        acc[n] = __builtin_amdgcn_mfma_i32_16x16x64_i8(af, bfr, acc[n], 0, 0, 0);
                    }
                }
#pragma unroll
                for (int n = 0; n < 4; ++n) {
                    bf16x4 zb;
#pragma unroll
                    for (int jr = 0; jr < 4; ++jr)
                        zb[jr] = (__bf16)(bv[n] + (float)acc[n][jr] * f[n]);
                    __builtin_nontemporal_store(zb,
                        (bf16x4*)(zsl + (size_t)t * 16384 + ((wq * 4 + n) * 64 + l) * 8));
                }

                lds_barrier();              // everyone done reading this step's slabs
                if (pf) *(i32x4*)(bufw + tid * 16) = p0;
                lds_barrier();              // staged slab visible
            }

            __syncthreads();                // drain NT z-stores before publish
            if (tid == 0)
                __hip_atomic_store(&F[512 + g * 32 + c], 1, __ATOMIC_RELEASE, __HIP_MEMORY_SCOPE_AGENT);
        }
    }
}

// ---------------------------------------------------------------------------
// Batch-axis softmax stats per hidden column.
// ---------------------------------------------------------------------------
__global__ void colstats_kernel(const float* __restrict__ encoded,
                                float* __restrict__ colmax,
                                float* __restrict__ rsinv)
{
    const int h = blockIdx.x;
    const int lane = threadIdx.x;  // 64
    float v[4];
#pragma unroll
    for (int r = 0; r < 4; ++r) v[r] = encoded[(size_t)(lane + 64 * r) * NH + h];
    float mx = fmaxf(fmaxf(v[0], v[1]), fmaxf(v[2], v[3]));
#pragma unroll
    for (int s = 1; s < 64; s <<= 1) mx = fmaxf(mx, __shfl_xor(mx, s));
    float sum = 0.f;
#pragma unroll
    for (int r = 0; r < 4; ++r) sum += __expf(v[r] - mx);
#pragma unroll
    for (int s = 1; s < 64; s <<= 1) sum += __shfl_xor(sum, s);
    if (lane == 0) { colmax[h] = mx; rsinv[h] = 1.0f / sum; }
}

// ---------------------------------------------------------------------------
// Decoder: 4 blocks x 256 threads.  a1 phase: 4-way h-split per batch
// (quarter = tid>>6) with LDS reduce; recurrence on quarter-0 threads.
// ---------------------------------------------------------------------------
__global__ void decoder_kernel(
    const float* __restrict__ encoded,
    const float* __restrict__ colmax, const float* __restrict__ rsinv,
    const float* __restrict__ dWih0, const float* __restrict__ dWhh0,
    const float* __restrict__ dbih0, const float* __restrict__ dbhh0,
    const float* __restrict__ dWih1, const float* __restrict__ dWhh1,
    const float* __restrict__ dbih1, const float* __restrict__ dbhh1,
    float* __restrict__ out)
{
    const int tid = threadIdx.x;          // 256
    const int bl  = tid & 63;             // local batch
    const int qh  = tid >> 6;             // h quarter
    const int b   = blockIdx.x * 64 + bl;

    __shared__ float part[4][64][4];

    float c1p[4] = {0.f, 0.f, 0.f, 0.f};
    const float* er = encoded + (size_t)b * NH;
#pragma unroll 1
    for (int h = qh * 128; h < qh * 128 + 128; h += 4) {
        const float4 ev = *(const float4*)(er + h);
        const float4 cm = *(const float4*)(colmax + h);
        const float4 rs = *(const float4*)(rsinv + h);
        float p0 = __expf(ev.x - cm.x) * rs.x;
        float p1 = __expf(ev.y - cm.y) * rs.y;
        float p2 = __expf(ev.z - cm.z) * rs.z;
        float p3 = __expf(ev.w - cm.w) * rs.w;
#pragma unroll
        for (int j = 0; j < 4; ++j) {
            const float4 w = *(const float4*)(dWih0 + (size_t)j * NH + h);
            c1p[j] += p0 * w.x + p1 * w.y + p2 * w.z + p3 * w.w;
        }
    }
#pragma unroll
    for (int j = 0; j < 4; ++j) part[qh][bl][j] = c1p[j];
    __syncthreads();
    if (qh != 0) return;

    float W0[16], Wi[16], W1[16];
#pragma unroll
    for (int e = 0; e < 16; ++e) { W0[e] = dWhh0[e]; Wi[e] = dWih1[e]; W1[e] = dWhh1[e]; }

    float c1[4], c2[4];
#pragma unroll
    for (int j = 0; j < 4; ++j) {
        c1[j] = dbih0[j] + dbhh0[j]
              + part[0][bl][j] + part[1][bl][j] + part[2][bl][j] + part[3][bl][j];
        c2[j] = dbih1[j] + dbhh1[j];
    }

    float h1[4] = {0.f, 0.f, 0.f, 0.f};
    float h2[4] = {0.f, 0.f, 0.f, 0.f};
    float* op = out + (size_t)b * NS * NV;

#pragma unroll 1
    for (int t = 0; t < NS; ++t) {
        float n1[4];
#pragma unroll
        for (int j = 0; j < 4; ++j)
            n1[j] = fast_tanh(c1[j] + W0[j*4+0]*h1[0] + W0[j*4+1]*h1[1]
                                    + W0[j*4+2]*h1[2] + W0[j*4+3]*h1[3]);
        float n2[4];
#pragma unroll
        for (int j = 0; j < 4; ++j)
            n2[j] = fast_tanh(c2[j] + Wi[j*4+0]*n1[0] + Wi[j*4+1]*n1[1]
                                    + Wi[j*4+2]*n1[2] + Wi[j*4+3]*n1[3]
                                    + W1[j*4+0]*h2[0] + W1[j*4+1]*h2[1]
                                    + W1[j*4+2]*h2[2] + W1[j*4+3]*h2[3]);
#pragma unroll
        for (int j = 0; j < 4; ++j) { h1[j] = n1[j]; h2[j] = n2[j]; }
        *(float4*)(op + (size_t)t * NV) = make_float4(n2[0], n2[1], n2[2], n2[3]);
    }
}

extern "C" void kernel_launch(void* const* d_in, const int* in_sizes, int n_in,
                              void* d_out, int out_size, void* d_ws, size_t ws_size,
                              hipStream_t stream)
{
    const float* x     = (const float*)d_in[0];
    const float* eWih0 = (const float*)d_in[1];
    const float* eWhh0 = (const float*)d_in[2];
    const float* ebih0 = (const float*)d_in[3];
    const float* ebhh0 = (const float*)d_in[4];
    const float* eWih1 = (const float*)d_in[5];
    const float* eWhh1 = (const float*)d_in[6];
    const float* ebih1 = (const float*)d_in[7];
    const float* ebhh1 = (const float*)d_in[8];
    const float* dWih0 = (const float*)d_in[9];
    const float* dWhh0 = (const float*)d_in[10];
    const float* dbih0 = (const float*)d_in[11];
    const float* dbhh0 = (const float*)d_in[12];
    const float* dWih1 = (const float*)d_in[13];
    const float* dWhh1 = (const float*)d_in[14];
    const float* dbih1 = (const float*)d_in[15];
    const float* dbhh1 = (const float*)d_in[16];

    char*  ws     = (char*)d_ws;
    float* enc    = (float*)(ws + ENC_OFF);
    float* colmax = (float*)(ws + CM_OFF);
    float* rsinv  = (float*)(ws + RS_OFF);

    hipFuncSetAttribute((const void*)persist_kernel,
                        hipFuncAttributeMaxDynamicSharedMemorySize, 147456);

    // zero flags
    hipMemsetAsync(d_ws, 0, 4096, stream);

    // one-shot weight quantization (i8 B-frags + per-col scales)
    prep_kernel<<<96, 256, 0, stream>>>(eWhh0, eWhh1, eWih1, ws);

    // persistent pipelined encoder (i8 weights fully CU-resident)
    persist_kernel<<<48, 512, 147456, stream>>>(x, eWih0, ebih0, ebhh0,
                                                ebih1, ebhh1, ws);

    colstats_kernel<<<NH, 64, 0, stream>>>(enc, colmax, rsinv);
    decoder_kernel<<<4, 256, 0, stream>>>(enc, colmax, rsinv,
                                          dWih0, dWhh0, dbih0, dbhh0,
                                          dWih1, dWhh1, dbih1, dbhh1,
                                          (float*)d_out);
}